// Round 1
// baseline (409.050 us; speedup 1.0000x reference)
//
#include <hip/hip_runtime.h>
#include <stdint.h>

#define B_ 2
#define S_ 2048
#define E_ 1024
#define H_ 16
#define HD_ 64
#define FF_ 4096
#define M_ 4096   // B*S

typedef short bf16x8 __attribute__((ext_vector_type(8)));
typedef float f32x4  __attribute__((ext_vector_type(4)));
typedef short shortx4 __attribute__((ext_vector_type(4)));

__device__ __forceinline__ short f2bf(float f) {
  uint32_t u = __builtin_bit_cast(uint32_t, f);
  u += 0x7fffu + ((u >> 16) & 1u);
  return (short)(u >> 16);
}
__device__ __forceinline__ float bf2f(short b) {
  uint32_t u = ((uint32_t)(uint16_t)b) << 16;
  return __builtin_bit_cast(float, u);
}

// async global->LDS, 16B per lane, wave-uniform LDS base + lane*16
#define GLDS16(g, l) __builtin_amdgcn_global_load_lds( \
    (const __attribute__((address_space(1))) unsigned int*)(g), \
    (__attribute__((address_space(3))) unsigned int*)(l), 16, 0, 0)

// ---------------------------------------------------------------- cast f32->bf16
__global__ void cast_f32_bf16(const float* __restrict__ in, short* __restrict__ out, int n) {
  int stride = gridDim.x * blockDim.x;
  for (int i = blockIdx.x * blockDim.x + threadIdx.x; i * 4 < n; i += stride) {
    float4 v = ((const float4*)in)[i];
    shortx4 o;
    o.x = f2bf(v.x); o.y = f2bf(v.y); o.z = f2bf(v.z); o.w = f2bf(v.w);
    ((shortx4*)out)[i] = o;
  }
}

// ---------------------------------------------------------------- GEMM  C = A * Bw^T
// A: M x K bf16 row-major.  Bw: N x K bf16 row-major (i.e. B^T layout).
// EPI: 0 = none, 1 = bias + relu, 2 = bias.   OutT: short (bf16) or float.
// m97 structure: 128x128 tile, BK=32, 4 waves (2x2), 4x4 16x16 frags per wave.
template<int EPI, typename OutT>
__global__ __launch_bounds__(256) void gemm_bt(
    const short* __restrict__ A, const short* __restrict__ Bw,
    OutT* __restrict__ C, const float* __restrict__ bias,
    int M, int N, int K)
{
  __shared__ short Al[128 * 32];
  __shared__ short Bl[128 * 32];
  const int tid  = threadIdx.x;
  const int w    = tid >> 6, lane = tid & 63;
  const int ntiles = N >> 7;
  const int tn = blockIdx.x % ntiles, tm = blockIdx.x / ntiles;
  const int m0 = tm << 7, n0 = tn << 7;
  const int wr = (w >> 1) << 6, wc = (w & 1) << 6;
  const int lr = lane & 15, lk = (lane >> 4) << 3;
  const int ra = lane >> 2, colA = (lane & 3) << 3;   // staging row/col within chunk

  f32x4 acc[4][4] = {};

  for (int k0 = 0; k0 < K; k0 += 32) {
    __syncthreads();
    // stage A,B tiles: 8 chunks of 16 rows x 32 cols each; wave w does chunks w, w+4
    #pragma unroll
    for (int i = 0; i < 2; ++i) {
      const int ch = w + (i << 2);
      GLDS16(A  + (size_t)(m0 + ch * 16 + ra) * K + k0 + colA, &Al[ch * 512]);
      GLDS16(Bw + (size_t)(n0 + ch * 16 + ra) * K + k0 + colA, &Bl[ch * 512]);
    }
    __syncthreads();
    bf16x8 af[4], bfr[4];
    #pragma unroll
    for (int i = 0; i < 4; ++i)
      af[i] = *(const bf16x8*)&Al[(wr + i * 16 + lr) * 32 + lk];
    #pragma unroll
    for (int j = 0; j < 4; ++j)
      bfr[j] = *(const bf16x8*)&Bl[(wc + j * 16 + lr) * 32 + lk];
    #pragma unroll
    for (int i = 0; i < 4; ++i)
      #pragma unroll
      for (int j = 0; j < 4; ++j)
        acc[i][j] = __builtin_amdgcn_mfma_f32_16x16x32_bf16(af[i], bfr[j], acc[i][j], 0, 0, 0);
  }

  const int lg = lane >> 4;
  #pragma unroll
  for (int j = 0; j < 4; ++j) {
    const int col = n0 + wc + j * 16 + lr;
    float bv = 0.f;
    if constexpr (EPI != 0) bv = bias[col];
    #pragma unroll
    for (int i = 0; i < 4; ++i) {
      #pragma unroll
      for (int r = 0; r < 4; ++r) {
        const int row = m0 + wr + i * 16 + lg * 4 + r;
        float v = acc[i][j][r] + bv;
        if constexpr (EPI == 1) v = fmaxf(v, 0.f);
        if constexpr (sizeof(OutT) == 2) C[(size_t)row * N + col] = f2bf(v);
        else                             C[(size_t)row * N + col] = v;
      }
    }
  }
}

// ---------------------------------------------------------------- causal flash attention
// kqv: (B*S, 3E) bf16, layout per row: [K(c=0) | Q(c=1) | V(c=2)], each c: h*64+d
// out: (B*S, E) bf16, col = h*64 + d
__global__ __launch_bounds__(256) void attn_kernel(
    const short* __restrict__ kqv, short* __restrict__ out)
{
  __shared__ short Kt[64][72];        // K rows (k) x d, padded
  __shared__ short Vt[64][72];        // transposed: d x k, padded
  __shared__ short Pl[4][16][72];     // per-wave P tile

  const int tid = threadIdx.x, w = tid >> 6, lane = tid & 63;
  const int qt = blockIdx.x;          // 0..31
  const int bh = blockIdx.y;          // 0..31
  const int b = bh >> 4, h = bh & 15;
  const int q0 = qt << 6;
  const int lr = lane & 15, lg = lane >> 4;

  // Q fragment: rows q0 + w*16 + lr, d = lg*8 + ks*32 .. +8
  const size_t qrowbase = (size_t)(b * S_ + q0 + w * 16 + lr) * 3072 + 1024 + h * 64;
  bf16x8 qf[2];
  qf[0] = *(const bf16x8*)&kqv[qrowbase + lg * 8];
  qf[1] = *(const bf16x8*)&kqv[qrowbase + 32 + lg * 8];

  f32x4 acc[4] = {};
  float m_run[4], l_run[4];
  #pragma unroll
  for (int r = 0; r < 4; ++r) { m_run[r] = -1e30f; l_run[r] = 0.f; }
  const float scale = 0.125f;

  const int skk = tid >> 3;           // 0..31 staging row
  const int sc  = (tid & 7) << 3;     // staging col (d)

  for (int kb = 0; kb <= q0; kb += 64) {
    // ---- stage K (row-major) and V (transposed) into LDS
    #pragma unroll
    for (int i = 0; i < 2; ++i) {
      const int krow = skk + i * 32;
      const size_t gb = (size_t)(b * S_ + kb + krow) * 3072 + h * 64 + sc;
      *(bf16x8*)&Kt[krow][sc] = *(const bf16x8*)&kqv[gb];          // c=0: K
      bf16x8 vv = *(const bf16x8*)&kqv[gb + 2048];                  // c=2: V
      #pragma unroll
      for (int e = 0; e < 8; ++e) Vt[sc + e][krow] = vv[e];
    }
    __syncthreads();

    // ---- S = Q K^T  (per wave: 16 q rows x 64 k cols)
    f32x4 sacc[4] = {};
    #pragma unroll
    for (int jt = 0; jt < 4; ++jt) {
      #pragma unroll
      for (int ks = 0; ks < 2; ++ks) {
        bf16x8 kf = *(const bf16x8*)&Kt[jt * 16 + lr][ks * 32 + lg * 8];
        sacc[jt] = __builtin_amdgcn_mfma_f32_16x16x32_bf16(qf[ks], kf, sacc[jt], 0, 0, 0);
      }
    }

    // ---- scale + causal mask + row max
    float rmax[4];
    #pragma unroll
    for (int r = 0; r < 4; ++r) rmax[r] = -1e30f;
    #pragma unroll
    for (int jt = 0; jt < 4; ++jt) {
      const int kpos = kb + jt * 16 + lr;
      #pragma unroll
      for (int r = 0; r < 4; ++r) {
        const int qrow = q0 + w * 16 + lg * 4 + r;
        float v = sacc[jt][r] * scale;
        v = (kpos <= qrow) ? v : -1e30f;
        sacc[jt][r] = v;
        rmax[r] = fmaxf(rmax[r], v);
      }
    }
    #pragma unroll
    for (int m = 8; m >= 1; m >>= 1)
      #pragma unroll
      for (int r = 0; r < 4; ++r) rmax[r] = fmaxf(rmax[r], __shfl_xor(rmax[r], m));

    // ---- online softmax update
    float alpha[4], rsum[4];
    #pragma unroll
    for (int r = 0; r < 4; ++r) {
      float mn = fmaxf(m_run[r], rmax[r]);
      alpha[r] = __expf(m_run[r] - mn);
      m_run[r] = mn;
      rsum[r] = 0.f;
    }
    #pragma unroll
    for (int jt = 0; jt < 4; ++jt)
      #pragma unroll
      for (int r = 0; r < 4; ++r) {
        float p = __expf(sacc[jt][r] - m_run[r]);
        sacc[jt][r] = p;
        rsum[r] += p;
      }
    #pragma unroll
    for (int m = 8; m >= 1; m >>= 1)
      #pragma unroll
      for (int r = 0; r < 4; ++r) rsum[r] += __shfl_xor(rsum[r], m);
    #pragma unroll
    for (int r = 0; r < 4; ++r) l_run[r] = l_run[r] * alpha[r] + rsum[r];
    #pragma unroll
    for (int dt = 0; dt < 4; ++dt)
      #pragma unroll
      for (int r = 0; r < 4; ++r) acc[dt][r] *= alpha[r];

    // ---- P -> LDS (bf16), then PV
    #pragma unroll
    for (int jt = 0; jt < 4; ++jt)
      #pragma unroll
      for (int r = 0; r < 4; ++r)
        Pl[w][lg * 4 + r][jt * 16 + lr] = f2bf(sacc[jt][r]);

    bf16x8 pa[2];
    pa[0] = *(const bf16x8*)&Pl[w][lr][lg * 8];
    pa[1] = *(const bf16x8*)&Pl[w][lr][32 + lg * 8];
    #pragma unroll
    for (int dt = 0; dt < 4; ++dt) {
      #pragma unroll
      for (int ks = 0; ks < 2; ++ks) {
        bf16x8 vb = *(const bf16x8*)&Vt[dt * 16 + lr][ks * 32 + lg * 8];
        acc[dt] = __builtin_amdgcn_mfma_f32_16x16x32_bf16(pa[ks], vb, acc[dt], 0, 0, 0);
      }
    }
    __syncthreads();
  }

  // ---- epilogue: normalize and store
  #pragma unroll
  for (int dt = 0; dt < 4; ++dt) {
    #pragma unroll
    for (int r = 0; r < 4; ++r) {
      const int qrow = q0 + w * 16 + lg * 4 + r;
      out[(size_t)(b * S_ + qrow) * E_ + h * 64 + dt * 16 + lr] = f2bf(acc[dt][r] / l_run[r]);
    }
  }
}

// ---------------------------------------------------------------- residual + LayerNorm
// FINAL=0: y f32 + res f32 -> LN(g,b) -> out bf16
// FINAL=1: y f32 + res bf16 -> LN(g,b) -> out f32
template<int FINAL>
__global__ __launch_bounds__(256) void ln_kernel(
    const float* __restrict__ y, const void* __restrict__ res,
    const float* __restrict__ gam, const float* __restrict__ bet,
    void* __restrict__ outp)
{
  const int row = blockIdx.x, tid = threadIdx.x, lane = tid & 63, w = tid >> 6;
  float4 v = ((const float4*)(y + (size_t)row * E_))[tid];
  float r[4];
  if constexpr (FINAL) {
    shortx4 rb = ((const shortx4*)((const short*)res + (size_t)row * E_))[tid];
    r[0] = v.x + bf2f(rb.x); r[1] = v.y + bf2f(rb.y);
    r[2] = v.z + bf2f(rb.z); r[3] = v.w + bf2f(rb.w);
  } else {
    float4 rv = ((const float4*)((const float*)res + (size_t)row * E_))[tid];
    r[0] = v.x + rv.x; r[1] = v.y + rv.y; r[2] = v.z + rv.z; r[3] = v.w + rv.w;
  }
  float s  = r[0] + r[1] + r[2] + r[3];
  float ss = r[0]*r[0] + r[1]*r[1] + r[2]*r[2] + r[3]*r[3];
  #pragma unroll
  for (int m = 32; m >= 1; m >>= 1) { s += __shfl_xor(s, m); ss += __shfl_xor(ss, m); }
  __shared__ float red[8];
  if (lane == 0) { red[w] = s; red[4 + w] = ss; }
  __syncthreads();
  s  = red[0] + red[1] + red[2] + red[3];
  ss = red[4] + red[5] + red[6] + red[7];
  const float mu  = s * (1.f / E_);
  const float var = ss * (1.f / E_) - mu * mu;
  const float rs  = rsqrtf(var + 1e-6f);
  float4 gv = ((const float4*)gam)[tid];
  float4 bv = ((const float4*)bet)[tid];
  float o0 = (r[0] - mu) * rs * gv.x + bv.x;
  float o1 = (r[1] - mu) * rs * gv.y + bv.y;
  float o2 = (r[2] - mu) * rs * gv.z + bv.z;
  float o3 = (r[3] - mu) * rs * gv.w + bv.w;
  if constexpr (FINAL) {
    float4 o; o.x = o0; o.y = o1; o.z = o2; o.w = o3;
    ((float4*)((float*)outp + (size_t)row * E_))[tid] = o;
  } else {
    shortx4 o; o.x = f2bf(o0); o.y = f2bf(o1); o.z = f2bf(o2); o.w = f2bf(o3);
    ((shortx4*)((short*)outp + (size_t)row * E_))[tid] = o;
  }
}

// ---------------------------------------------------------------- launch
extern "C" void kernel_launch(void* const* d_in, const int* in_sizes, int n_in,
                              void* d_out, int out_size, void* d_ws, size_t ws_size,
                              hipStream_t stream) {
  const float* x      = (const float*)d_in[0];
  // d_in[1] = mask (deterministic causal triu) -- not needed
  const float* w_kqv  = (const float*)d_in[2];
  const float* w_o    = (const float*)d_in[3];
  const float* w_up   = (const float*)d_in[4];
  const float* b_up   = (const float*)d_in[5];
  const float* w_down = (const float*)d_in[6];
  const float* b_down = (const float*)d_in[7];
  const float* g1     = (const float*)d_in[8];
  const float* b1     = (const float*)d_in[9];
  const float* g2     = (const float*)d_in[10];
  const float* b2     = (const float*)d_in[11];
  float* out = (float*)d_out;

  char* ws = (char*)d_ws;
  short* xb     = (short*)(ws);                         // 8 MB  x bf16 (dead after kqv GEMM)
  short* wkqvb  = (short*)(ws + ((size_t)8  << 20));    // 6 MB
  short* wob    = (short*)(ws + ((size_t)14 << 20));    // 2 MB
  short* wupb   = (short*)(ws + ((size_t)16 << 20));    // 8 MB
  short* wdownb = (short*)(ws + ((size_t)24 << 20));    // 8 MB
  short* kqv    = (short*)(ws + ((size_t)32 << 20));    // 24 MB (R2)
  float* proj   = (float*)(ws + ((size_t)32 << 20));    // 16 MB (R2, after kqv dead)
  short* hbuf   = (short*)(ws + ((size_t)32 << 20));    // 32 MB (R2, after proj dead)
  short* attno  = (short*)(ws + ((size_t)64 << 20));    // 8 MB
  short* xln    = (short*)(ws + ((size_t)72 << 20));    // 8 MB
  float* down   = (float*)(ws + ((size_t)80 << 20));    // 16 MB  -> total 96 MB

  // casts
  auto cast = [&](const float* src, short* dst, int n) {
    int blocks = n / (256 * 4); if (blocks > 2048) blocks = 2048;
    cast_f32_bf16<<<blocks, 256, 0, stream>>>(src, dst, n);
  };
  cast(x,      xb,     M_ * E_);
  cast(w_kqv,  wkqvb,  3 * E_ * E_);
  cast(w_o,    wob,    E_ * E_);
  cast(w_up,   wupb,   FF_ * E_);
  cast(w_down, wdownb, E_ * FF_);

  // kqv = x @ w_kqv^T  (4096 x 3072)
  gemm_bt<0, short><<<24 * 32, 256, 0, stream>>>(xb, wkqvb, kqv, nullptr, M_, 3 * E_, E_);
  // attention
  attn_kernel<<<dim3(S_ / 64, B_ * H_), 256, 0, stream>>>(kqv, attno);
  // proj = attno @ w_o^T  (4096 x 1024, f32)
  gemm_bt<0, float><<<8 * 32, 256, 0, stream>>>(attno, wob, proj, nullptr, M_, E_, E_);
  // x_ln = LN(proj + x) -> bf16
  ln_kernel<0><<<M_, 256, 0, stream>>>(proj, x, g1, b1, xln);
  // h = relu(x_ln @ w_up^T + b_up)  (4096 x 4096, bf16)
  gemm_bt<1, short><<<32 * 32, 256, 0, stream>>>(xln, wupb, hbuf, b_up, M_, FF_, E_);
  // down = h @ w_down^T + b_down  (4096 x 1024, f32)
  gemm_bt<2, float><<<8 * 32, 256, 0, stream>>>(hbuf, wdownb, down, b_down, M_, E_, FF_);
  // out = LN(down + x_ln) -> f32
  ln_kernel<1><<<M_, 256, 0, stream>>>(down, xln, g2, b2, out);
}

// Round 3
// 343.044 us; speedup vs baseline: 1.1924x; 1.1924x over previous
//
#include <hip/hip_runtime.h>
#include <stdint.h>

#define B_ 2
#define S_ 2048
#define E_ 1024
#define H_ 16
#define HD_ 64
#define FF_ 4096
#define M_ 4096   // B*S

typedef short bf16x8 __attribute__((ext_vector_type(8)));
typedef float f32x4  __attribute__((ext_vector_type(4)));
typedef short shortx4 __attribute__((ext_vector_type(4)));

#define MFMA16(a,b,c) __builtin_amdgcn_mfma_f32_16x16x32_bf16(a,b,c,0,0,0)

__device__ __forceinline__ short f2bf(float f) {
  uint32_t u = __builtin_bit_cast(uint32_t, f);
  u += 0x7fffu + ((u >> 16) & 1u);
  return (short)(u >> 16);
}
__device__ __forceinline__ float bf2f(short b) {
  uint32_t u = ((uint32_t)(uint16_t)b) << 16;
  return __builtin_bit_cast(float, u);
}

// async global->LDS, 16B per lane, wave-uniform LDS base + lane*16 (per-lane global src)
#define GLDS16(g, l) __builtin_amdgcn_global_load_lds( \
    (const __attribute__((address_space(1))) unsigned int*)(g), \
    (__attribute__((address_space(3))) unsigned int*)(l), 16, 0, 0)

// ---------------------------------------------------------------- cast f32->bf16
__global__ void cast_f32_bf16(const float* __restrict__ in, short* __restrict__ out, int n) {
  int stride = gridDim.x * blockDim.x;
  for (int i = blockIdx.x * blockDim.x + threadIdx.x; i * 4 < n; i += stride) {
    float4 v = ((const float4*)in)[i];
    shortx4 o;
    o.x = f2bf(v.x); o.y = f2bf(v.y); o.z = f2bf(v.z); o.w = f2bf(v.w);
    ((shortx4*)out)[i] = o;
  }
}

// ---------------------------------------------------------------- GEMM  C = A * Bw^T
// A: M x K bf16 row-major.  Bw: N x K bf16 row-major.  m97 structure.
template<int EPI, typename OutT>
__global__ __launch_bounds__(256) void gemm_bt(
    const short* __restrict__ A, const short* __restrict__ Bw,
    OutT* __restrict__ C, const float* __restrict__ bias,
    int M, int N, int K)
{
  __shared__ short Al[128 * 32];
  __shared__ short Bl[128 * 32];
  const int tid  = threadIdx.x;
  const int w    = tid >> 6, lane = tid & 63;
  const int ntiles = N >> 7;
  // bijective XCD swizzle (all our grids are %8 == 0)
  const int nwg = gridDim.x;
  const int bid = blockIdx.x;
  const int swz = (bid & 7) * (nwg >> 3) + (bid >> 3);
  const int tn = swz % ntiles, tm = swz / ntiles;
  const int m0 = tm << 7, n0 = tn << 7;
  const int wr = (w >> 1) << 6, wc = (w & 1) << 6;
  const int lr = lane & 15, lk = (lane >> 4) << 3;
  const int ra = lane >> 2, colA = (lane & 3) << 3;

  f32x4 acc[4][4] = {};

  for (int k0 = 0; k0 < K; k0 += 32) {
    __syncthreads();
    #pragma unroll
    for (int i = 0; i < 2; ++i) {
      const int ch = w + (i << 2);
      GLDS16(A  + (size_t)(m0 + ch * 16 + ra) * K + k0 + colA, &Al[ch * 512]);
      GLDS16(Bw + (size_t)(n0 + ch * 16 + ra) * K + k0 + colA, &Bl[ch * 512]);
    }
    __syncthreads();
    bf16x8 af[4], bfr[4];
    #pragma unroll
    for (int i = 0; i < 4; ++i)
      af[i] = *(const bf16x8*)&Al[(wr + i * 16 + lr) * 32 + lk];
    #pragma unroll
    for (int j = 0; j < 4; ++j)
      bfr[j] = *(const bf16x8*)&Bl[(wc + j * 16 + lr) * 32 + lk];
    #pragma unroll
    for (int i = 0; i < 4; ++i)
      #pragma unroll
      for (int j = 0; j < 4; ++j)
        acc[i][j] = MFMA16(af[i], bfr[j], acc[i][j]);
  }

  const int lg = lane >> 4;
  #pragma unroll
  for (int j = 0; j < 4; ++j) {
    const int col = n0 + wc + j * 16 + lr;
    float bv = 0.f;
    if constexpr (EPI != 0) bv = bias[col];
    #pragma unroll
    for (int i = 0; i < 4; ++i) {
      #pragma unroll
      for (int r = 0; r < 4; ++r) {
        const int row = m0 + wr + i * 16 + lg * 4 + r;
        float v = acc[i][j][r] + bv;
        if constexpr (EPI == 1) v = fmaxf(v, 0.f);
        if constexpr (sizeof(OutT) == 2) C[(size_t)row * N + col] = f2bf(v);
        else                             C[(size_t)row * N + col] = v;
      }
    }
  }
}

// ---------------------------------------------------------------- causal flash attention
// Round-1 verified per-tile math; paired q-tiles (p, 31-p) for load balance.
// kqv: (B*S, 3E) bf16, row = [K | Q | V], each section col = h*64 + d
__global__ __launch_bounds__(256) void attn_kernel(
    const short* __restrict__ kqv, short* __restrict__ out)
{
  __shared__ short Kt[64][72];        // K rows (k) x d, padded
  __shared__ short Vt[64][72];        // transposed: d x k, padded
  __shared__ short Pl[4][16][72];     // per-wave P tile

  const int tid = threadIdx.x, w = tid >> 6, lane = tid & 63;
  const int p = blockIdx.x;           // 0..15
  const int bh = blockIdx.y;          // 0..31
  const int b = bh >> 4, h = bh & 15;
  const int q0lo = p << 6, q0hi = (31 - p) << 6;
  const int nkb = 32 - p;             // k-blocks for the hi tile
  const int lr = lane & 15, lg = lane >> 4;

  // Q fragments: rows q0 + w*16 + lr, d = ks*32 + lg*8 ..+8
  const size_t rowlo = (size_t)(b * S_ + q0lo + w * 16 + lr) * 3072 + 1024 + h * 64;
  const size_t rowhi = (size_t)(b * S_ + q0hi + w * 16 + lr) * 3072 + 1024 + h * 64;
  bf16x8 qlo[2], qhi[2];
  qlo[0] = *(const bf16x8*)&kqv[rowlo];      qlo[1] = *(const bf16x8*)&kqv[rowlo + 32];
  qhi[0] = *(const bf16x8*)&kqv[rowhi];      qhi[1] = *(const bf16x8*)&kqv[rowhi + 32];
  qlo[0] = *(const bf16x8*)&kqv[rowlo + lg * 8];
  qlo[1] = *(const bf16x8*)&kqv[rowlo + 32 + lg * 8];
  qhi[0] = *(const bf16x8*)&kqv[rowhi + lg * 8];
  qhi[1] = *(const bf16x8*)&kqv[rowhi + 32 + lg * 8];

  f32x4 aclo[4] = {}, achi[4] = {};
  float mlo[4], llo[4], mhi[4], lhi[4];
  #pragma unroll
  for (int r = 0; r < 4; ++r) { mlo[r] = mhi[r] = -1e30f; llo[r] = lhi[r] = 0.f; }

  const int skk = tid >> 3;           // 0..31 staging row
  const int sc  = (tid & 7) << 3;     // staging col (d)

  for (int kbi = 0; kbi < nkb; ++kbi) {
    const int kb = kbi << 6;
    // ---- stage K (row-major) and V (transposed) into LDS
    #pragma unroll
    for (int i = 0; i < 2; ++i) {
      const int krow = skk + i * 32;
      const size_t gb = (size_t)(b * S_ + kb + krow) * 3072 + h * 64 + sc;
      *(bf16x8*)&Kt[krow][sc] = *(const bf16x8*)&kqv[gb];          // c=0: K
      bf16x8 vv = *(const bf16x8*)&kqv[gb + 2048];                  // c=2: V
      #pragma unroll
      for (int e = 0; e < 8; ++e) Vt[sc + e][krow] = vv[e];
    }
    __syncthreads();

    // ---- per-tile processing (round-1 verified math)
    auto process = [&](const bf16x8 (&qf)[2], f32x4 (&acc)[4],
                       float (&m_run)[4], float (&l_run)[4], int q0) {
      // S = Q K^T  (per wave: 16 q rows x 64 k cols)
      f32x4 sacc[4] = {};
      #pragma unroll
      for (int jt = 0; jt < 4; ++jt) {
        #pragma unroll
        for (int ks = 0; ks < 2; ++ks) {
          bf16x8 kf = *(const bf16x8*)&Kt[jt * 16 + lr][ks * 32 + lg * 8];
          sacc[jt] = MFMA16(qf[ks], kf, sacc[jt]);
        }
      }
      // scale + causal mask + row max
      float rmax[4];
      #pragma unroll
      for (int r = 0; r < 4; ++r) rmax[r] = -1e30f;
      #pragma unroll
      for (int jt = 0; jt < 4; ++jt) {
        const int kpos = kb + jt * 16 + lr;
        #pragma unroll
        for (int r = 0; r < 4; ++r) {
          const int qrow = q0 + w * 16 + lg * 4 + r;
          float v = sacc[jt][r] * 0.125f;
          v = (kpos <= qrow) ? v : -1e30f;
          sacc[jt][r] = v;
          rmax[r] = fmaxf(rmax[r], v);
        }
      }
      #pragma unroll
      for (int m = 8; m >= 1; m >>= 1)
        #pragma unroll
        for (int r = 0; r < 4; ++r) rmax[r] = fmaxf(rmax[r], __shfl_xor(rmax[r], m));
      // online softmax update
      float alpha[4], rsum[4];
      #pragma unroll
      for (int r = 0; r < 4; ++r) {
        float mn = fmaxf(m_run[r], rmax[r]);
        alpha[r] = __expf(m_run[r] - mn);
        m_run[r] = mn;
        rsum[r] = 0.f;
      }
      #pragma unroll
      for (int jt = 0; jt < 4; ++jt)
        #pragma unroll
        for (int r = 0; r < 4; ++r) {
          float pv = __expf(sacc[jt][r] - m_run[r]);
          sacc[jt][r] = pv;
          rsum[r] += pv;
        }
      #pragma unroll
      for (int m = 8; m >= 1; m >>= 1)
        #pragma unroll
        for (int r = 0; r < 4; ++r) rsum[r] += __shfl_xor(rsum[r], m);
      #pragma unroll
      for (int r = 0; r < 4; ++r) l_run[r] = l_run[r] * alpha[r] + rsum[r];
      #pragma unroll
      for (int dt = 0; dt < 4; ++dt)
        #pragma unroll
        for (int r = 0; r < 4; ++r) acc[dt][r] *= alpha[r];
      // P -> LDS (bf16), then PV
      #pragma unroll
      for (int jt = 0; jt < 4; ++jt)
        #pragma unroll
        for (int r = 0; r < 4; ++r)
          Pl[w][lg * 4 + r][jt * 16 + lr] = f2bf(sacc[jt][r]);
      bf16x8 pa[2];
      pa[0] = *(const bf16x8*)&Pl[w][lr][lg * 8];
      pa[1] = *(const bf16x8*)&Pl[w][lr][32 + lg * 8];
      #pragma unroll
      for (int dt = 0; dt < 4; ++dt) {
        #pragma unroll
        for (int ks = 0; ks < 2; ++ks) {
          bf16x8 vb = *(const bf16x8*)&Vt[dt * 16 + lr][ks * 32 + lg * 8];
          acc[dt] = MFMA16(pa[ks], vb, acc[dt]);
        }
      }
    };

    process(qhi, achi, mhi, lhi, q0hi);
    if (kb <= q0lo + w * 16 + 15) process(qlo, aclo, mlo, llo, q0lo);
    __syncthreads();
  }

  // ---- epilogue: normalize and store both tiles
  #pragma unroll
  for (int dt = 0; dt < 4; ++dt) {
    #pragma unroll
    for (int r = 0; r < 4; ++r) {
      const int d = h * 64 + dt * 16 + lr;
      const int qlo_row = q0lo + w * 16 + lg * 4 + r;
      const int qhi_row = q0hi + w * 16 + lg * 4 + r;
      out[(size_t)(b * S_ + qlo_row) * E_ + d] = f2bf(aclo[dt][r] / llo[r]);
      out[(size_t)(b * S_ + qhi_row) * E_ + d] = f2bf(achi[dt][r] / lhi[r]);
    }
  }
}

// ---------------------------------------------------------------- residual + LayerNorm
template<int FINAL>
__global__ __launch_bounds__(256) void ln_kernel(
    const float* __restrict__ y, const void* __restrict__ res,
    const float* __restrict__ gam, const float* __restrict__ bet,
    void* __restrict__ outp)
{
  const int row = blockIdx.x, tid = threadIdx.x, lane = tid & 63, w = tid >> 6;
  float4 v = ((const float4*)(y + (size_t)row * E_))[tid];
  float r[4];
  if constexpr (FINAL) {
    shortx4 rb = ((const shortx4*)((const short*)res + (size_t)row * E_))[tid];
    r[0] = v.x + bf2f(rb.x); r[1] = v.y + bf2f(rb.y);
    r[2] = v.z + bf2f(rb.z); r[3] = v.w + bf2f(rb.w);
  } else {
    float4 rv = ((const float4*)((const float*)res + (size_t)row * E_))[tid];
    r[0] = v.x + rv.x; r[1] = v.y + rv.y; r[2] = v.z + rv.z; r[3] = v.w + rv.w;
  }
  float s  = r[0] + r[1] + r[2] + r[3];
  float ss = r[0]*r[0] + r[1]*r[1] + r[2]*r[2] + r[3]*r[3];
  #pragma unroll
  for (int m = 32; m >= 1; m >>= 1) { s += __shfl_xor(s, m); ss += __shfl_xor(ss, m); }
  __shared__ float red[8];
  if (lane == 0) { red[w] = s; red[4 + w] = ss; }
  __syncthreads();
  s  = red[0] + red[1] + red[2] + red[3];
  ss = red[4] + red[5] + red[6] + red[7];
  const float mu  = s * (1.f / E_);
  const float var = ss * (1.f / E_) - mu * mu;
  const float rs  = rsqrtf(var + 1e-6f);
  float4 gv = ((const float4*)gam)[tid];
  float4 bv = ((const float4*)bet)[tid];
  float o0 = (r[0] - mu) * rs * gv.x + bv.x;
  float o1 = (r[1] - mu) * rs * gv.y + bv.y;
  float o2 = (r[2] - mu) * rs * gv.z + bv.z;
  float o3 = (r[3] - mu) * rs * gv.w + bv.w;
  if constexpr (FINAL) {
    float4 o; o.x = o0; o.y = o1; o.z = o2; o.w = o3;
    ((float4*)((float*)outp + (size_t)row * E_))[tid] = o;
  } else {
    shortx4 o; o.x = f2bf(o0); o.y = f2bf(o1); o.z = f2bf(o2); o.w = f2bf(o3);
    ((shortx4*)((short*)outp + (size_t)row * E_))[tid] = o;
  }
}

// ---------------------------------------------------------------- launch
extern "C" void kernel_launch(void* const* d_in, const int* in_sizes, int n_in,
                              void* d_out, int out_size, void* d_ws, size_t ws_size,
                              hipStream_t stream) {
  const float* x      = (const float*)d_in[0];
  const float* w_kqv  = (const float*)d_in[2];
  const float* w_o    = (const float*)d_in[3];
  const float* w_up   = (const float*)d_in[4];
  const float* b_up   = (const float*)d_in[5];
  const float* w_down = (const float*)d_in[6];
  const float* b_down = (const float*)d_in[7];
  const float* g1     = (const float*)d_in[8];
  const float* b1     = (const float*)d_in[9];
  const float* g2     = (const float*)d_in[10];
  const float* b2     = (const float*)d_in[11];
  float* out = (float*)d_out;

  char* ws = (char*)d_ws;
  short* xb     = (short*)(ws);                         // 8 MB
  short* wkqvb  = (short*)(ws + ((size_t)8  << 20));    // 6 MB
  short* wob    = (short*)(ws + ((size_t)14 << 20));    // 2 MB
  short* wupb   = (short*)(ws + ((size_t)16 << 20));    // 8 MB
  short* wdownb = (short*)(ws + ((size_t)24 << 20));    // 8 MB
  short* kqv    = (short*)(ws + ((size_t)32 << 20));    // 24 MB
  float* proj   = (float*)(ws + ((size_t)32 << 20));    // 16 MB (after kqv dead)
  short* hbuf   = (short*)(ws + ((size_t)32 << 20));    // 32 MB (after proj dead)
  short* attno  = (short*)(ws + ((size_t)64 << 20));    // 8 MB
  short* xln    = (short*)(ws + ((size_t)72 << 20));    // 8 MB
  float* down   = (float*)(ws + ((size_t)80 << 20));    // 16 MB

  auto cast = [&](const float* src, short* dst, int n) {
    int blocks = n / (256 * 4); if (blocks > 2048) blocks = 2048;
    cast_f32_bf16<<<blocks, 256, 0, stream>>>(src, dst, n);
  };
  cast(x,      xb,     M_ * E_);
  cast(w_kqv,  wkqvb,  3 * E_ * E_);
  cast(w_o,    wob,    E_ * E_);
  cast(w_up,   wupb,   FF_ * E_);
  cast(w_down, wdownb, E_ * FF_);

  gemm_bt<0, short><<<24 * 32, 256, 0, stream>>>(xb, wkqvb, kqv, nullptr, M_, 3 * E_, E_);
  attn_kernel<<<dim3(16, B_ * H_), 256, 0, stream>>>(kqv, attno);
  gemm_bt<0, float><<<8 * 32, 256, 0, stream>>>(attno, wob, proj, nullptr, M_, E_, E_);
  ln_kernel<0><<<M_, 256, 0, stream>>>(proj, x, g1, b1, xln);
  gemm_bt<1, short><<<32 * 32, 256, 0, stream>>>(xln, wupb, hbuf, b_up, M_, FF_, E_);
  gemm_bt<2, float><<<8 * 32, 256, 0, stream>>>(hbuf, wdownb, down, b_down, M_, E_, FF_);
  ln_kernel<1><<<M_, 256, 0, stream>>>(down, xln, g2, b2, out);
}

// Round 4
// 301.784 us; speedup vs baseline: 1.3554x; 1.1367x over previous
//
#include <hip/hip_runtime.h>
#include <stdint.h>

#define B_ 2
#define S_ 2048
#define E_ 1024
#define H_ 16
#define HD_ 64
#define FF_ 4096
#define M_ 4096   // B*S

typedef short bf16x8 __attribute__((ext_vector_type(8)));
typedef float f32x4  __attribute__((ext_vector_type(4)));
typedef short shortx4 __attribute__((ext_vector_type(4)));

#define MFMA16(a,b,c) __builtin_amdgcn_mfma_f32_16x16x32_bf16(a,b,c,0,0,0)

__device__ __forceinline__ short f2bf(float f) {
  uint32_t u = __builtin_bit_cast(uint32_t, f);
  u += 0x7fffu + ((u >> 16) & 1u);
  return (short)(u >> 16);
}
__device__ __forceinline__ float bf2f(short b) {
  uint32_t u = ((uint32_t)(uint16_t)b) << 16;
  return __builtin_bit_cast(float, u);
}

// async global->LDS, 16B per lane, wave-uniform LDS base + lane*16 (per-lane global src)
#define GLDS16(g, l) __builtin_amdgcn_global_load_lds( \
    (const __attribute__((address_space(1))) unsigned int*)(g), \
    (__attribute__((address_space(3))) unsigned int*)(l), 16, 0, 0)

// ---------------------------------------------------------------- cast f32->bf16
__global__ void cast_f32_bf16(const float* __restrict__ in, short* __restrict__ out, int n) {
  int stride = gridDim.x * blockDim.x;
  for (int i = blockIdx.x * blockDim.x + threadIdx.x; i * 4 < n; i += stride) {
    float4 v = ((const float4*)in)[i];
    shortx4 o;
    o.x = f2bf(v.x); o.y = f2bf(v.y); o.z = f2bf(v.z); o.w = f2bf(v.w);
    ((shortx4*)out)[i] = o;
  }
}

// ---------------------------------------------------------------- GEMM  C = A * Bw^T
// A: M x K bf16 row-major.  Bw: N x K bf16 row-major.  m97 structure.
// BM = 128 (waves 2x2 of 64x64, acc 4x4) or 64 (waves 2x2 of 32x64, acc 2x4).
template<int BM, int EPI, typename OutT>
__global__ __launch_bounds__(256) void gemm_bt(
    const short* __restrict__ A, const short* __restrict__ Bw,
    OutT* __restrict__ C, const float* __restrict__ bias,
    int M, int N, int K)
{
  constexpr int MI = BM / 32;          // M-frags per wave
  constexpr int ACH = BM / 64;         // A staging issues per wave
  __shared__ short Al[BM * 32];
  __shared__ short Bl[128 * 32];
  const int tid  = threadIdx.x;
  const int w    = tid >> 6, lane = tid & 63;
  const int ntiles = N >> 7;
  // bijective XCD swizzle (all our grids are %8 == 0)
  const int nwg = gridDim.x;
  const int bid = blockIdx.x;
  const int swz = (bid & 7) * (nwg >> 3) + (bid >> 3);
  const int tn = swz % ntiles, tm = swz / ntiles;
  const int m0 = tm * BM, n0 = tn << 7;
  const int wr = (w >> 1) * (16 * MI), wc = (w & 1) << 6;
  const int lr = lane & 15, lk = (lane >> 4) << 3;
  const int ra = lane >> 2, colA = (lane & 3) << 3;

  f32x4 acc[MI][4] = {};

  for (int k0 = 0; k0 < K; k0 += 32) {
    __syncthreads();
    #pragma unroll
    for (int i = 0; i < ACH; ++i) {
      const int ch = w + (i << 2);
      GLDS16(A + (size_t)(m0 + ch * 16 + ra) * K + k0 + colA, &Al[ch * 512]);
    }
    #pragma unroll
    for (int i = 0; i < 2; ++i) {
      const int ch = w + (i << 2);
      GLDS16(Bw + (size_t)(n0 + ch * 16 + ra) * K + k0 + colA, &Bl[ch * 512]);
    }
    __syncthreads();
    bf16x8 af[MI], bfr[4];
    #pragma unroll
    for (int i = 0; i < MI; ++i)
      af[i] = *(const bf16x8*)&Al[(wr + i * 16 + lr) * 32 + lk];
    #pragma unroll
    for (int j = 0; j < 4; ++j)
      bfr[j] = *(const bf16x8*)&Bl[(wc + j * 16 + lr) * 32 + lk];
    #pragma unroll
    for (int i = 0; i < MI; ++i)
      #pragma unroll
      for (int j = 0; j < 4; ++j)
        acc[i][j] = MFMA16(af[i], bfr[j], acc[i][j]);
  }

  const int lg = lane >> 4;
  #pragma unroll
  for (int j = 0; j < 4; ++j) {
    const int col = n0 + wc + j * 16 + lr;
    float bv = 0.f;
    if constexpr (EPI != 0) bv = bias[col];
    #pragma unroll
    for (int i = 0; i < MI; ++i) {
      #pragma unroll
      for (int r = 0; r < 4; ++r) {
        const int row = m0 + wr + i * 16 + lg * 4 + r;
        float v = acc[i][j][r] + bv;
        if constexpr (EPI == 1) v = fmaxf(v, 0.f);
        if constexpr (sizeof(OutT) == 2) C[(size_t)row * N + col] = f2bf(v);
        else                             C[(size_t)row * N + col] = v;
      }
    }
  }
}

// ---------------------------------------------------------------- causal flash attention
// Round-1 verified per-tile math; paired q-tiles (p, 31-p); V column XOR-swizzle.
// kqv: (B*S, 3E) bf16, row = [K | Q | V], each section col = h*64 + d
__global__ __launch_bounds__(256) void attn_kernel(
    const short* __restrict__ kqv, short* __restrict__ out)
{
  __shared__ short Kt[64][72];        // K rows (k) x d
  __shared__ short Vt[64][72];        // transposed: d x k, col k XOR-swizzled by 8*((d>>3)&7)
  __shared__ short Pl[4][16][72];     // per-wave P tile

  const int tid = threadIdx.x, w = tid >> 6, lane = tid & 63;
  const int p = blockIdx.x;           // 0..15
  const int bh = blockIdx.y;          // 0..31
  const int b = bh >> 4, h = bh & 15;
  const int q0lo = p << 6, q0hi = (31 - p) << 6;
  const int nkb = 32 - p;             // k-blocks for the hi tile
  const int lr = lane & 15, lg = lane >> 4;

  // Q fragments: rows q0 + w*16 + lr, d = ks*32 + lg*8 ..+8
  const size_t rowlo = (size_t)(b * S_ + q0lo + w * 16 + lr) * 3072 + 1024 + h * 64;
  const size_t rowhi = (size_t)(b * S_ + q0hi + w * 16 + lr) * 3072 + 1024 + h * 64;
  bf16x8 qlo[2], qhi[2];
  qlo[0] = *(const bf16x8*)&kqv[rowlo + lg * 8];
  qlo[1] = *(const bf16x8*)&kqv[rowlo + 32 + lg * 8];
  qhi[0] = *(const bf16x8*)&kqv[rowhi + lg * 8];
  qhi[1] = *(const bf16x8*)&kqv[rowhi + 32 + lg * 8];

  f32x4 aclo[4] = {}, achi[4] = {};
  float mlo[4], llo[4], mhi[4], lhi[4];
  #pragma unroll
  for (int r = 0; r < 4; ++r) { mlo[r] = mhi[r] = -1e30f; llo[r] = lhi[r] = 0.f; }

  const int skk = tid >> 3;           // 0..31 staging row (k)
  const int sc  = (tid & 7) << 3;     // staging col (d)
  const int vws = (tid & 7) << 3;     // V write swizzle: 8*((sc+e)>>3 & 7) = 8*(tid&7)

  for (int kbi = 0; kbi < nkb; ++kbi) {
    const int kb = kbi << 6;
    // ---- stage K (row-major) and V (transposed, col-swizzled) into LDS
    #pragma unroll
    for (int i = 0; i < 2; ++i) {
      const int krow = skk + i * 32;
      const size_t gb = (size_t)(b * S_ + kb + krow) * 3072 + h * 64 + sc;
      *(bf16x8*)&Kt[krow][sc] = *(const bf16x8*)&kqv[gb];          // c=0: K
      bf16x8 vv = *(const bf16x8*)&kqv[gb + 2048];                  // c=2: V
      const int kc = krow ^ vws;
      #pragma unroll
      for (int e = 0; e < 8; ++e) Vt[sc + e][kc] = vv[e];
    }
    __syncthreads();

    // ---- per-tile processing (round-1 verified math)
    auto process = [&](const bf16x8 (&qf)[2], f32x4 (&acc)[4],
                       float (&m_run)[4], float (&l_run)[4], int q0) {
      // S = Q K^T  (per wave: 16 q rows x 64 k cols)
      f32x4 sacc[4] = {};
      #pragma unroll
      for (int jt = 0; jt < 4; ++jt) {
        #pragma unroll
        for (int ks = 0; ks < 2; ++ks) {
          bf16x8 kf = *(const bf16x8*)&Kt[jt * 16 + lr][ks * 32 + lg * 8];
          sacc[jt] = MFMA16(qf[ks], kf, sacc[jt]);
        }
      }
      // scale + causal mask + row max
      float rmax[4];
      #pragma unroll
      for (int r = 0; r < 4; ++r) rmax[r] = -1e30f;
      #pragma unroll
      for (int jt = 0; jt < 4; ++jt) {
        const int kpos = kb + jt * 16 + lr;
        #pragma unroll
        for (int r = 0; r < 4; ++r) {
          const int qrow = q0 + w * 16 + lg * 4 + r;
          float v = sacc[jt][r] * 0.125f;
          v = (kpos <= qrow) ? v : -1e30f;
          sacc[jt][r] = v;
          rmax[r] = fmaxf(rmax[r], v);
        }
      }
      #pragma unroll
      for (int m = 8; m >= 1; m >>= 1)
        #pragma unroll
        for (int r = 0; r < 4; ++r) rmax[r] = fmaxf(rmax[r], __shfl_xor(rmax[r], m));
      // online softmax update
      float alpha[4], rsum[4];
      #pragma unroll
      for (int r = 0; r < 4; ++r) {
        float mn = fmaxf(m_run[r], rmax[r]);
        alpha[r] = __expf(m_run[r] - mn);
        m_run[r] = mn;
        rsum[r] = 0.f;
      }
      #pragma unroll
      for (int jt = 0; jt < 4; ++jt)
        #pragma unroll
        for (int r = 0; r < 4; ++r) {
          float pv = __expf(sacc[jt][r] - m_run[r]);
          sacc[jt][r] = pv;
          rsum[r] += pv;
        }
      #pragma unroll
      for (int m = 8; m >= 1; m >>= 1)
        #pragma unroll
        for (int r = 0; r < 4; ++r) rsum[r] += __shfl_xor(rsum[r], m);
      #pragma unroll
      for (int r = 0; r < 4; ++r) l_run[r] = l_run[r] * alpha[r] + rsum[r];
      #pragma unroll
      for (int dt = 0; dt < 4; ++dt)
        #pragma unroll
        for (int r = 0; r < 4; ++r) acc[dt][r] *= alpha[r];
      // P -> LDS (bf16), then PV
      #pragma unroll
      for (int jt = 0; jt < 4; ++jt)
        #pragma unroll
        for (int r = 0; r < 4; ++r)
          Pl[w][lg * 4 + r][jt * 16 + lr] = f2bf(sacc[jt][r]);
      bf16x8 pa[2];
      pa[0] = *(const bf16x8*)&Pl[w][lr][lg * 8];
      pa[1] = *(const bf16x8*)&Pl[w][lr][32 + lg * 8];
      #pragma unroll
      for (int dt = 0; dt < 4; ++dt) {
        const int vswz = (2 * dt + (lr >> 3)) << 3;   // 8*((row>>3)&7), row = dt*16+lr
        #pragma unroll
        for (int ks = 0; ks < 2; ++ks) {
          bf16x8 vb = *(const bf16x8*)&Vt[dt * 16 + lr][(ks * 32 + lg * 8) ^ vswz];
          acc[dt] = MFMA16(pa[ks], vb, acc[dt]);
        }
      }
    };

    process(qhi, achi, mhi, lhi, q0hi);
    if (kb <= q0lo + w * 16 + 15) process(qlo, aclo, mlo, llo, q0lo);
    __syncthreads();
  }

  // ---- epilogue: normalize and store both tiles
  #pragma unroll
  for (int dt = 0; dt < 4; ++dt) {
    #pragma unroll
    for (int r = 0; r < 4; ++r) {
      const int d = h * 64 + dt * 16 + lr;
      const int qlo_row = q0lo + w * 16 + lg * 4 + r;
      const int qhi_row = q0hi + w * 16 + lg * 4 + r;
      out[(size_t)(b * S_ + qlo_row) * E_ + d] = f2bf(aclo[dt][r] / llo[r]);
      out[(size_t)(b * S_ + qhi_row) * E_ + d] = f2bf(achi[dt][r] / lhi[r]);
    }
  }
}

// ---------------------------------------------------------------- residual + LayerNorm
template<int FINAL>
__global__ __launch_bounds__(256) void ln_kernel(
    const float* __restrict__ y, const void* __restrict__ res,
    const float* __restrict__ gam, const float* __restrict__ bet,
    void* __restrict__ outp)
{
  const int row = blockIdx.x, tid = threadIdx.x, lane = tid & 63, w = tid >> 6;
  float4 v = ((const float4*)(y + (size_t)row * E_))[tid];
  float r[4];
  if constexpr (FINAL) {
    shortx4 rb = ((const shortx4*)((const short*)res + (size_t)row * E_))[tid];
    r[0] = v.x + bf2f(rb.x); r[1] = v.y + bf2f(rb.y);
    r[2] = v.z + bf2f(rb.z); r[3] = v.w + bf2f(rb.w);
  } else {
    float4 rv = ((const float4*)((const float*)res + (size_t)row * E_))[tid];
    r[0] = v.x + rv.x; r[1] = v.y + rv.y; r[2] = v.z + rv.z; r[3] = v.w + rv.w;
  }
  float s  = r[0] + r[1] + r[2] + r[3];
  float ss = r[0]*r[0] + r[1]*r[1] + r[2]*r[2] + r[3]*r[3];
  #pragma unroll
  for (int m = 32; m >= 1; m >>= 1) { s += __shfl_xor(s, m); ss += __shfl_xor(ss, m); }
  __shared__ float red[8];
  if (lane == 0) { red[w] = s; red[4 + w] = ss; }
  __syncthreads();
  s  = red[0] + red[1] + red[2] + red[3];
  ss = red[4] + red[5] + red[6] + red[7];
  const float mu  = s * (1.f / E_);
  const float var = ss * (1.f / E_) - mu * mu;
  const float rs  = rsqrtf(var + 1e-6f);
  float4 gv = ((const float4*)gam)[tid];
  float4 bv = ((const float4*)bet)[tid];
  float o0 = (r[0] - mu) * rs * gv.x + bv.x;
  float o1 = (r[1] - mu) * rs * gv.y + bv.y;
  float o2 = (r[2] - mu) * rs * gv.z + bv.z;
  float o3 = (r[3] - mu) * rs * gv.w + bv.w;
  if constexpr (FINAL) {
    float4 o; o.x = o0; o.y = o1; o.z = o2; o.w = o3;
    ((float4*)((float*)outp + (size_t)row * E_))[tid] = o;
  } else {
    shortx4 o; o.x = f2bf(o0); o.y = f2bf(o1); o.z = f2bf(o2); o.w = f2bf(o3);
    ((shortx4*)((short*)outp + (size_t)row * E_))[tid] = o;
  }
}

// ---------------------------------------------------------------- launch
extern "C" void kernel_launch(void* const* d_in, const int* in_sizes, int n_in,
                              void* d_out, int out_size, void* d_ws, size_t ws_size,
                              hipStream_t stream) {
  const float* x      = (const float*)d_in[0];
  const float* w_kqv  = (const float*)d_in[2];
  const float* w_o    = (const float*)d_in[3];
  const float* w_up   = (const float*)d_in[4];
  const float* b_up   = (const float*)d_in[5];
  const float* w_down = (const float*)d_in[6];
  const float* b_down = (const float*)d_in[7];
  const float* g1     = (const float*)d_in[8];
  const float* b1     = (const float*)d_in[9];
  const float* g2     = (const float*)d_in[10];
  const float* b2     = (const float*)d_in[11];
  float* out = (float*)d_out;

  char* ws = (char*)d_ws;
  short* xb     = (short*)(ws);                         // 8 MB
  short* wkqvb  = (short*)(ws + ((size_t)8  << 20));    // 6 MB
  short* wob    = (short*)(ws + ((size_t)14 << 20));    // 2 MB
  short* wupb   = (short*)(ws + ((size_t)16 << 20));    // 8 MB
  short* wdownb = (short*)(ws + ((size_t)24 << 20));    // 8 MB
  short* kqv    = (short*)(ws + ((size_t)32 << 20));    // 24 MB
  float* proj   = (float*)(ws + ((size_t)32 << 20));    // 16 MB (after kqv dead)
  short* hbuf   = (short*)(ws + ((size_t)32 << 20));    // 32 MB (after proj dead)
  short* attno  = (short*)(ws + ((size_t)64 << 20));    // 8 MB
  short* xln    = (short*)(ws + ((size_t)72 << 20));    // 8 MB
  float* down   = (float*)(ws + ((size_t)80 << 20));    // 16 MB

  auto cast = [&](const float* src, short* dst, int n) {
    int blocks = n / (256 * 4); if (blocks > 2048) blocks = 2048;
    cast_f32_bf16<<<blocks, 256, 0, stream>>>(src, dst, n);
  };
  cast(x,      xb,     M_ * E_);
  cast(w_kqv,  wkqvb,  3 * E_ * E_);
  cast(w_o,    wob,    E_ * E_);
  cast(w_up,   wupb,   FF_ * E_);
  cast(w_down, wdownb, E_ * FF_);

  gemm_bt<128, 0, short><<<24 * 32, 256, 0, stream>>>(xb, wkqvb, kqv, nullptr, M_, 3 * E_, E_);
  attn_kernel<<<dim3(16, B_ * H_), 256, 0, stream>>>(kqv, attno);
  gemm_bt<64, 0, float><<<64 * 8, 256, 0, stream>>>(attno, wob, proj, nullptr, M_, E_, E_);
  ln_kernel<0><<<M_, 256, 0, stream>>>(proj, x, g1, b1, xln);
  gemm_bt<128, 1, short><<<32 * 32, 256, 0, stream>>>(xln, wupb, hbuf, b_up, M_, FF_, E_);
  gemm_bt<64, 2, float><<<64 * 8, 256, 0, stream>>>(hbuf, wdownb, down, b_down, M_, E_, FF_);
  ln_kernel<1><<<M_, 256, 0, stream>>>(down, xln, g2, b2, out);
}

// Round 5
// 288.519 us; speedup vs baseline: 1.4178x; 1.0460x over previous
//
#include <hip/hip_runtime.h>
#include <stdint.h>

#define B_ 2
#define S_ 2048
#define E_ 1024
#define H_ 16
#define HD_ 64
#define FF_ 4096
#define M_ 4096   // B*S

typedef short bf16x8 __attribute__((ext_vector_type(8)));
typedef float f32x4  __attribute__((ext_vector_type(4)));
typedef short shortx4 __attribute__((ext_vector_type(4)));

#define MFMA16(a,b,c) __builtin_amdgcn_mfma_f32_16x16x32_bf16(a,b,c,0,0,0)

__device__ __forceinline__ short f2bf(float f) {
  uint32_t u = __builtin_bit_cast(uint32_t, f);
  u += 0x7fffu + ((u >> 16) & 1u);
  return (short)(u >> 16);
}
__device__ __forceinline__ float bf2f(short b) {
  uint32_t u = ((uint32_t)(uint16_t)b) << 16;
  return __builtin_bit_cast(float, u);
}

// DPP row-rotate (16-lane row), VALU-pipe cross-lane: ROW_ROR:N = 0x120|N
template<int CTRL>
__device__ __forceinline__ float dpp_ror(float x) {
  return __builtin_bit_cast(float,
    __builtin_amdgcn_update_dpp(0, __builtin_bit_cast(int, x), CTRL, 0xF, 0xF, true));
}
__device__ __forceinline__ float dpp_max16(float v) {
  v = fmaxf(v, dpp_ror<0x128>(v));
  v = fmaxf(v, dpp_ror<0x124>(v));
  v = fmaxf(v, dpp_ror<0x122>(v));
  v = fmaxf(v, dpp_ror<0x121>(v));
  return v;
}
__device__ __forceinline__ float dpp_sum16(float v) {
  v += dpp_ror<0x128>(v);
  v += dpp_ror<0x124>(v);
  v += dpp_ror<0x122>(v);
  v += dpp_ror<0x121>(v);
  return v;
}

// async global->LDS, 16B per lane, wave-uniform LDS base + lane*16 (per-lane global src)
#define GLDS16(g, l) __builtin_amdgcn_global_load_lds( \
    (const __attribute__((address_space(1))) unsigned int*)(g), \
    (__attribute__((address_space(3))) unsigned int*)(l), 16, 0, 0)

// ---------------------------------------------------------------- cast f32->bf16
__global__ void cast_f32_bf16(const float* __restrict__ in, short* __restrict__ out, int n) {
  int stride = gridDim.x * blockDim.x;
  for (int i = blockIdx.x * blockDim.x + threadIdx.x; i * 4 < n; i += stride) {
    float4 v = ((const float4*)in)[i];
    shortx4 o;
    o.x = f2bf(v.x); o.y = f2bf(v.y); o.z = f2bf(v.z); o.w = f2bf(v.w);
    ((shortx4*)out)[i] = o;
  }
}

// ---------------------------------------------------------------- GEMM  C = A * Bw^T
// A: M x K bf16 row-major.  Bw: N x K bf16 row-major.  m97 structure.
// BM = 128 (waves 2x2 of 64x64, acc 4x4) or 64 (waves 2x2 of 32x64, acc 2x4).
template<int BM, int EPI, typename OutT>
__global__ __launch_bounds__(256) void gemm_bt(
    const short* __restrict__ A, const short* __restrict__ Bw,
    OutT* __restrict__ C, const float* __restrict__ bias,
    int M, int N, int K)
{
  constexpr int MI = BM / 32;          // M-frags per wave
  constexpr int ACH = BM / 64;         // A staging issues per wave
  __shared__ short Al[BM * 32];
  __shared__ short Bl[128 * 32];
  const int tid  = threadIdx.x;
  const int w    = tid >> 6, lane = tid & 63;
  const int ntiles = N >> 7;
  // bijective XCD swizzle (all our grids are %8 == 0)
  const int nwg = gridDim.x;
  const int bid = blockIdx.x;
  const int swz = (bid & 7) * (nwg >> 3) + (bid >> 3);
  const int tn = swz % ntiles, tm = swz / ntiles;
  const int m0 = tm * BM, n0 = tn << 7;
  const int wr = (w >> 1) * (16 * MI), wc = (w & 1) << 6;
  const int lr = lane & 15, lk = (lane >> 4) << 3;
  const int ra = lane >> 2, colA = (lane & 3) << 3;

  f32x4 acc[MI][4] = {};

  for (int k0 = 0; k0 < K; k0 += 32) {
    __syncthreads();
    #pragma unroll
    for (int i = 0; i < ACH; ++i) {
      const int ch = w + (i << 2);
      GLDS16(A + (size_t)(m0 + ch * 16 + ra) * K + k0 + colA, &Al[ch * 512]);
    }
    #pragma unroll
    for (int i = 0; i < 2; ++i) {
      const int ch = w + (i << 2);
      GLDS16(Bw + (size_t)(n0 + ch * 16 + ra) * K + k0 + colA, &Bl[ch * 512]);
    }
    __syncthreads();
    bf16x8 af[MI], bfr[4];
    #pragma unroll
    for (int i = 0; i < MI; ++i)
      af[i] = *(const bf16x8*)&Al[(wr + i * 16 + lr) * 32 + lk];
    #pragma unroll
    for (int j = 0; j < 4; ++j)
      bfr[j] = *(const bf16x8*)&Bl[(wc + j * 16 + lr) * 32 + lk];
    #pragma unroll
    for (int i = 0; i < MI; ++i)
      #pragma unroll
      for (int j = 0; j < 4; ++j)
        acc[i][j] = MFMA16(af[i], bfr[j], acc[i][j]);
  }

  const int lg = lane >> 4;
  #pragma unroll
  for (int j = 0; j < 4; ++j) {
    const int col = n0 + wc + j * 16 + lr;
    float bv = 0.f;
    if constexpr (EPI != 0) bv = bias[col];
    #pragma unroll
    for (int i = 0; i < MI; ++i) {
      #pragma unroll
      for (int r = 0; r < 4; ++r) {
        const int row = m0 + wr + i * 16 + lg * 4 + r;
        float v = acc[i][j][r] + bv;
        if constexpr (EPI == 1) v = fmaxf(v, 0.f);
        if constexpr (sizeof(OutT) == 2) C[(size_t)row * N + col] = f2bf(v);
        else                             C[(size_t)row * N + col] = v;
      }
    }
  }
}

// ---------------------------------------------------------------- causal flash attention
// Paired q-tiles (p, 31-p); V column XOR-swizzle; DPP softmax reductions;
// Q pre-scaled by 1/8 (exact in bf16); setprio around MFMA clusters.
// kqv: (B*S, 3E) bf16, row = [K | Q | V], each section col = h*64 + d
__global__ __launch_bounds__(256) void attn_kernel(
    const short* __restrict__ kqv, short* __restrict__ out)
{
  __shared__ short Kt[64][72];        // K rows (k) x d
  __shared__ short Vt[64][72];        // transposed: d x k, col k XOR-swizzled by 8*((d>>3)&7)
  __shared__ short Pl[4][16][72];     // per-wave P tile

  const int tid = threadIdx.x, w = tid >> 6, lane = tid & 63;
  const int p = blockIdx.x;           // 0..15
  const int bh = blockIdx.y;          // 0..31
  const int b = bh >> 4, h = bh & 15;
  const int q0lo = p << 6, q0hi = (31 - p) << 6;
  const int nkb = 32 - p;             // k-blocks for the hi tile
  const int lr = lane & 15, lg = lane >> 4;

  // Q fragments: rows q0 + w*16 + lr, d = ks*32 + lg*8 ..+8; pre-scaled by 1/8 (exact)
  const size_t rowlo = (size_t)(b * S_ + q0lo + w * 16 + lr) * 3072 + 1024 + h * 64;
  const size_t rowhi = (size_t)(b * S_ + q0hi + w * 16 + lr) * 3072 + 1024 + h * 64;
  bf16x8 qlo[2], qhi[2];
  qlo[0] = *(const bf16x8*)&kqv[rowlo + lg * 8];
  qlo[1] = *(const bf16x8*)&kqv[rowlo + 32 + lg * 8];
  qhi[0] = *(const bf16x8*)&kqv[rowhi + lg * 8];
  qhi[1] = *(const bf16x8*)&kqv[rowhi + 32 + lg * 8];
  #pragma unroll
  for (int ks = 0; ks < 2; ++ks)
    #pragma unroll
    for (int e = 0; e < 8; ++e) {
      qlo[ks][e] = f2bf(bf2f(qlo[ks][e]) * 0.125f);
      qhi[ks][e] = f2bf(bf2f(qhi[ks][e]) * 0.125f);
    }

  f32x4 aclo[4] = {}, achi[4] = {};
  float mlo[4], llo[4], mhi[4], lhi[4];
  #pragma unroll
  for (int r = 0; r < 4; ++r) { mlo[r] = mhi[r] = -1e30f; llo[r] = lhi[r] = 0.f; }

  const int skk = tid >> 3;           // 0..31 staging row (k)
  const int sc  = (tid & 7) << 3;     // staging col (d)
  const int vws = (tid & 7) << 3;     // V write swizzle: 8*((sc+e)>>3 & 7) = 8*(tid&7)

  for (int kbi = 0; kbi < nkb; ++kbi) {
    const int kb = kbi << 6;
    // ---- stage K (row-major) and V (transposed, col-swizzled) into LDS
    #pragma unroll
    for (int i = 0; i < 2; ++i) {
      const int krow = skk + i * 32;
      const size_t gb = (size_t)(b * S_ + kb + krow) * 3072 + h * 64 + sc;
      *(bf16x8*)&Kt[krow][sc] = *(const bf16x8*)&kqv[gb];          // c=0: K
      bf16x8 vv = *(const bf16x8*)&kqv[gb + 2048];                  // c=2: V
      const int kc = krow ^ vws;
      #pragma unroll
      for (int e = 0; e < 8; ++e) Vt[sc + e][kc] = vv[e];
    }
    __syncthreads();

    // ---- per-tile processing
    auto process = [&](const bf16x8 (&qf)[2], f32x4 (&acc)[4],
                       float (&m_run)[4], float (&l_run)[4], int q0) {
      // S = Q K^T  (per wave: 16 q rows x 64 k cols)
      f32x4 sacc[4] = {};
      __builtin_amdgcn_s_setprio(1);
      #pragma unroll
      for (int jt = 0; jt < 4; ++jt) {
        #pragma unroll
        for (int ks = 0; ks < 2; ++ks) {
          bf16x8 kf = *(const bf16x8*)&Kt[jt * 16 + lr][ks * 32 + lg * 8];
          sacc[jt] = MFMA16(qf[ks], kf, sacc[jt]);
        }
      }
      __builtin_amdgcn_s_setprio(0);
      // causal mask + row max (scale already folded into Q)
      float rmax[4];
      #pragma unroll
      for (int r = 0; r < 4; ++r) rmax[r] = -1e30f;
      #pragma unroll
      for (int jt = 0; jt < 4; ++jt) {
        const int kpos = kb + jt * 16 + lr;
        #pragma unroll
        for (int r = 0; r < 4; ++r) {
          const int qrow = q0 + w * 16 + lg * 4 + r;
          float v = sacc[jt][r];
          v = (kpos <= qrow) ? v : -1e30f;
          sacc[jt][r] = v;
          rmax[r] = fmaxf(rmax[r], v);
        }
      }
      #pragma unroll
      for (int r = 0; r < 4; ++r) rmax[r] = dpp_max16(rmax[r]);
      // online softmax update
      float alpha[4], rsum[4];
      #pragma unroll
      for (int r = 0; r < 4; ++r) {
        float mn = fmaxf(m_run[r], rmax[r]);
        alpha[r] = __expf(m_run[r] - mn);
        m_run[r] = mn;
        rsum[r] = 0.f;
      }
      #pragma unroll
      for (int jt = 0; jt < 4; ++jt)
        #pragma unroll
        for (int r = 0; r < 4; ++r) {
          float pv = __expf(sacc[jt][r] - m_run[r]);
          sacc[jt][r] = pv;
          rsum[r] += pv;
        }
      #pragma unroll
      for (int r = 0; r < 4; ++r) rsum[r] = dpp_sum16(rsum[r]);
      #pragma unroll
      for (int r = 0; r < 4; ++r) l_run[r] = l_run[r] * alpha[r] + rsum[r];
      #pragma unroll
      for (int dt = 0; dt < 4; ++dt)
        #pragma unroll
        for (int r = 0; r < 4; ++r) acc[dt][r] *= alpha[r];
      // P -> LDS (bf16), then PV
      #pragma unroll
      for (int jt = 0; jt < 4; ++jt)
        #pragma unroll
        for (int r = 0; r < 4; ++r)
          Pl[w][lg * 4 + r][jt * 16 + lr] = f2bf(sacc[jt][r]);
      bf16x8 pa[2];
      pa[0] = *(const bf16x8*)&Pl[w][lr][lg * 8];
      pa[1] = *(const bf16x8*)&Pl[w][lr][32 + lg * 8];
      __builtin_amdgcn_s_setprio(1);
      #pragma unroll
      for (int dt = 0; dt < 4; ++dt) {
        const int vswz = (2 * dt + (lr >> 3)) << 3;   // 8*((row>>3)&7), row = dt*16+lr
        #pragma unroll
        for (int ks = 0; ks < 2; ++ks) {
          bf16x8 vb = *(const bf16x8*)&Vt[dt * 16 + lr][(ks * 32 + lg * 8) ^ vswz];
          acc[dt] = MFMA16(pa[ks], vb, acc[dt]);
        }
      }
      __builtin_amdgcn_s_setprio(0);
    };

    process(qhi, achi, mhi, lhi, q0hi);
    if (kb <= q0lo + w * 16 + 15) process(qlo, aclo, mlo, llo, q0lo);
    __syncthreads();
  }

  // ---- epilogue: normalize and store both tiles
  #pragma unroll
  for (int dt = 0; dt < 4; ++dt) {
    #pragma unroll
    for (int r = 0; r < 4; ++r) {
      const int d = h * 64 + dt * 16 + lr;
      const int qlo_row = q0lo + w * 16 + lg * 4 + r;
      const int qhi_row = q0hi + w * 16 + lg * 4 + r;
      out[(size_t)(b * S_ + qlo_row) * E_ + d] = f2bf(aclo[dt][r] / llo[r]);
      out[(size_t)(b * S_ + qhi_row) * E_ + d] = f2bf(achi[dt][r] / lhi[r]);
    }
  }
}

// ---------------------------------------------------------------- residual + LayerNorm
template<int FINAL>
__global__ __launch_bounds__(256) void ln_kernel(
    const float* __restrict__ y, const void* __restrict__ res,
    const float* __restrict__ gam, const float* __restrict__ bet,
    void* __restrict__ outp)
{
  const int row = blockIdx.x, tid = threadIdx.x, lane = tid & 63, w = tid >> 6;
  float4 v = ((const float4*)(y + (size_t)row * E_))[tid];
  float r[4];
  if constexpr (FINAL) {
    shortx4 rb = ((const shortx4*)((const short*)res + (size_t)row * E_))[tid];
    r[0] = v.x + bf2f(rb.x); r[1] = v.y + bf2f(rb.y);
    r[2] = v.z + bf2f(rb.z); r[3] = v.w + bf2f(rb.w);
  } else {
    float4 rv = ((const float4*)((const float*)res + (size_t)row * E_))[tid];
    r[0] = v.x + rv.x; r[1] = v.y + rv.y; r[2] = v.z + rv.z; r[3] = v.w + rv.w;
  }
  float s  = r[0] + r[1] + r[2] + r[3];
  float ss = r[0]*r[0] + r[1]*r[1] + r[2]*r[2] + r[3]*r[3];
  #pragma unroll
  for (int m = 32; m >= 1; m >>= 1) { s += __shfl_xor(s, m); ss += __shfl_xor(ss, m); }
  __shared__ float red[8];
  if (lane == 0) { red[w] = s; red[4 + w] = ss; }
  __syncthreads();
  s  = red[0] + red[1] + red[2] + red[3];
  ss = red[4] + red[5] + red[6] + red[7];
  const float mu  = s * (1.f / E_);
  const float var = ss * (1.f / E_) - mu * mu;
  const float rs  = rsqrtf(var + 1e-6f);
  float4 gv = ((const float4*)gam)[tid];
  float4 bv = ((const float4*)bet)[tid];
  float o0 = (r[0] - mu) * rs * gv.x + bv.x;
  float o1 = (r[1] - mu) * rs * gv.y + bv.y;
  float o2 = (r[2] - mu) * rs * gv.z + bv.z;
  float o3 = (r[3] - mu) * rs * gv.w + bv.w;
  if constexpr (FINAL) {
    float4 o; o.x = o0; o.y = o1; o.z = o2; o.w = o3;
    ((float4*)((float*)outp + (size_t)row * E_))[tid] = o;
  } else {
    shortx4 o; o.x = f2bf(o0); o.y = f2bf(o1); o.z = f2bf(o2); o.w = f2bf(o3);
    ((shortx4*)((short*)outp + (size_t)row * E_))[tid] = o;
  }
}

// ---------------------------------------------------------------- launch
extern "C" void kernel_launch(void* const* d_in, const int* in_sizes, int n_in,
                              void* d_out, int out_size, void* d_ws, size_t ws_size,
                              hipStream_t stream) {
  const float* x      = (const float*)d_in[0];
  const float* w_kqv  = (const float*)d_in[2];
  const float* w_o    = (const float*)d_in[3];
  const float* w_up   = (const float*)d_in[4];
  const float* b_up   = (const float*)d_in[5];
  const float* w_down = (const float*)d_in[6];
  const float* b_down = (const float*)d_in[7];
  const float* g1     = (const float*)d_in[8];
  const float* b1     = (const float*)d_in[9];
  const float* g2     = (const float*)d_in[10];
  const float* b2     = (const float*)d_in[11];
  float* out = (float*)d_out;

  char* ws = (char*)d_ws;
  short* xb     = (short*)(ws);                         // 8 MB
  short* wkqvb  = (short*)(ws + ((size_t)8  << 20));    // 6 MB
  short* wob    = (short*)(ws + ((size_t)14 << 20));    // 2 MB
  short* wupb   = (short*)(ws + ((size_t)16 << 20));    // 8 MB
  short* wdownb = (short*)(ws + ((size_t)24 << 20));    // 8 MB
  short* kqv    = (short*)(ws + ((size_t)32 << 20));    // 24 MB
  float* proj   = (float*)(ws + ((size_t)32 << 20));    // 16 MB (after kqv dead)
  short* hbuf   = (short*)(ws + ((size_t)32 << 20));    // 32 MB (after proj dead)
  short* attno  = (short*)(ws + ((size_t)64 << 20));    // 8 MB
  short* xln    = (short*)(ws + ((size_t)72 << 20));    // 8 MB
  float* down   = (float*)(ws + ((size_t)80 << 20));    // 16 MB

  auto cast = [&](const float* src, short* dst, int n) {
    int blocks = n / (256 * 4); if (blocks > 2048) blocks = 2048;
    cast_f32_bf16<<<blocks, 256, 0, stream>>>(src, dst, n);
  };
  cast(x,      xb,     M_ * E_);
  cast(w_kqv,  wkqvb,  3 * E_ * E_);
  cast(w_o,    wob,    E_ * E_);
  cast(w_up,   wupb,   FF_ * E_);
  cast(w_down, wdownb, E_ * FF_);

  gemm_bt<128, 0, short><<<24 * 32, 256, 0, stream>>>(xb, wkqvb, kqv, nullptr, M_, 3 * E_, E_);
  attn_kernel<<<dim3(16, B_ * H_), 256, 0, stream>>>(kqv, attno);
  gemm_bt<64, 0, float><<<64 * 8, 256, 0, stream>>>(attno, wob, proj, nullptr, M_, E_, E_);
  ln_kernel<0><<<M_, 256, 0, stream>>>(proj, x, g1, b1, xln);
  gemm_bt<128, 1, short><<<32 * 32, 256, 0, stream>>>(xln, wupb, hbuf, b_up, M_, FF_, E_);
  gemm_bt<64, 2, float><<<64 * 8, 256, 0, stream>>>(hbuf, wdownb, down, b_down, M_, E_, FF_);
  ln_kernel<1><<<M_, 256, 0, stream>>>(down, xln, g2, b2, out);
}

// Round 6
// 277.265 us; speedup vs baseline: 1.4753x; 1.0406x over previous
//
#include <hip/hip_runtime.h>
#include <stdint.h>

#define B_ 2
#define S_ 2048
#define E_ 1024
#define H_ 16
#define HD_ 64
#define FF_ 4096
#define M_ 4096   // B*S

typedef short bf16x8 __attribute__((ext_vector_type(8)));
typedef float f32x4  __attribute__((ext_vector_type(4)));
typedef short shortx4 __attribute__((ext_vector_type(4)));

#define MFMA16(a,b,c) __builtin_amdgcn_mfma_f32_16x16x32_bf16(a,b,c,0,0,0)

__device__ __forceinline__ short f2bf(float f) {
  uint32_t u = __builtin_bit_cast(uint32_t, f);
  u += 0x7fffu + ((u >> 16) & 1u);
  return (short)(u >> 16);
}
__device__ __forceinline__ float bf2f(short b) {
  uint32_t u = ((uint32_t)(uint16_t)b) << 16;
  return __builtin_bit_cast(float, u);
}

// DPP row-rotate (16-lane row), VALU-pipe cross-lane: ROW_ROR:N = 0x120|N
template<int CTRL>
__device__ __forceinline__ float dpp_ror(float x) {
  return __builtin_bit_cast(float,
    __builtin_amdgcn_update_dpp(0, __builtin_bit_cast(int, x), CTRL, 0xF, 0xF, true));
}
__device__ __forceinline__ float dpp_max16(float v) {
  v = fmaxf(v, dpp_ror<0x128>(v));
  v = fmaxf(v, dpp_ror<0x124>(v));
  v = fmaxf(v, dpp_ror<0x122>(v));
  v = fmaxf(v, dpp_ror<0x121>(v));
  return v;
}
__device__ __forceinline__ float dpp_sum16(float v) {
  v += dpp_ror<0x128>(v);
  v += dpp_ror<0x124>(v);
  v += dpp_ror<0x122>(v);
  v += dpp_ror<0x121>(v);
  return v;
}

// async global->LDS, 16B per lane, wave-uniform LDS base + lane*16 (per-lane global src)
#define GLDS16(g, l) __builtin_amdgcn_global_load_lds( \
    (const __attribute__((address_space(1))) unsigned int*)(g), \
    (__attribute__((address_space(3))) unsigned int*)(l), 16, 0, 0)

// ---------------------------------------------------------------- fused cast f32->bf16 (all 5 arrays)
// segments (f32 elems): x 4194304 | wkqv 3145728 | wo 1048576 | wup 4194304 | wdown 4194304
__global__ void cast_all(const float* __restrict__ x, const float* __restrict__ wkqv,
                         const float* __restrict__ wo, const float* __restrict__ wup,
                         const float* __restrict__ wdown,
                         short* __restrict__ xb, short* __restrict__ wkqvb,
                         short* __restrict__ wob, short* __restrict__ wupb,
                         short* __restrict__ wdownb) {
  const int stride = gridDim.x * blockDim.x;
  for (int i = blockIdx.x * blockDim.x + threadIdx.x; i < 4194304; i += stride) {
    const int e = i << 2;
    const float* src; short* dst; int off;
    if (e < 4194304)       { src = x;     dst = xb;     off = e; }
    else if (e < 7340032)  { src = wkqv;  dst = wkqvb;  off = e - 4194304; }
    else if (e < 8388608)  { src = wo;    dst = wob;    off = e - 7340032; }
    else if (e < 12582912) { src = wup;   dst = wupb;   off = e - 8388608; }
    else                   { src = wdown; dst = wdownb; off = e - 12582912; }
    float4 v = *(const float4*)(src + off);
    shortx4 o;
    o.x = f2bf(v.x); o.y = f2bf(v.y); o.z = f2bf(v.z); o.w = f2bf(v.w);
    *(shortx4*)(dst + off) = o;
  }
}

// ---------------------------------------------------------------- GEMM  C = A * Bw^T
// A: M x K bf16 row-major.  Bw: N x K bf16 row-major.  m97 structure, BM=128.
// SK: split-K factor. SK=1: C0 with EPI epilogue. SK=2: y-slice s writes partial
// (s==0 ? C0 : C1), EPI ignored (bias folded downstream).
template<int SK, int EPI, typename OutT>
__global__ __launch_bounds__(256) void gemm_bt(
    const short* __restrict__ A, const short* __restrict__ Bw,
    OutT* __restrict__ C0, OutT* __restrict__ C1, const float* __restrict__ bias,
    int M, int N, int K)
{
  __shared__ short Al[128 * 32];
  __shared__ short Bl[128 * 32];
  const int tid  = threadIdx.x;
  const int w    = tid >> 6, lane = tid & 63;
  const int ntiles = N >> 7;
  // bijective XCD swizzle (gridDim.x always %8 == 0 here)
  const int nwg = gridDim.x;
  const int bid = blockIdx.x;
  const int swz = (bid & 7) * (nwg >> 3) + (bid >> 3);
  const int tn = swz % ntiles, tm = swz / ntiles;
  const int m0 = tm << 7, n0 = tn << 7;
  const int wr = (w >> 1) << 6, wc = (w & 1) << 6;
  const int lr = lane & 15, lk = (lane >> 4) << 3;
  const int ra = lane >> 2, colA = (lane & 3) << 3;

  const int kper = K / SK;
  const int kbeg = (SK > 1) ? (int)blockIdx.y * kper : 0;
  const int kend = kbeg + kper;
  OutT* __restrict__ C = (SK > 1 && blockIdx.y) ? C1 : C0;

  f32x4 acc[4][4] = {};

  for (int k0 = kbeg; k0 < kend; k0 += 32) {
    __syncthreads();
    #pragma unroll
    for (int i = 0; i < 2; ++i) {
      const int ch = w + (i << 2);
      GLDS16(A  + (size_t)(m0 + ch * 16 + ra) * K + k0 + colA, &Al[ch * 512]);
      GLDS16(Bw + (size_t)(n0 + ch * 16 + ra) * K + k0 + colA, &Bl[ch * 512]);
    }
    __syncthreads();
    bf16x8 af[4], bfr[4];
    #pragma unroll
    for (int i = 0; i < 4; ++i)
      af[i] = *(const bf16x8*)&Al[(wr + i * 16 + lr) * 32 + lk];
    #pragma unroll
    for (int j = 0; j < 4; ++j)
      bfr[j] = *(const bf16x8*)&Bl[(wc + j * 16 + lr) * 32 + lk];
    #pragma unroll
    for (int i = 0; i < 4; ++i)
      #pragma unroll
      for (int j = 0; j < 4; ++j)
        acc[i][j] = MFMA16(af[i], bfr[j], acc[i][j]);
  }

  const int lg = lane >> 4;
  #pragma unroll
  for (int j = 0; j < 4; ++j) {
    const int col = n0 + wc + j * 16 + lr;
    float bv = 0.f;
    if constexpr (SK == 1 && EPI != 0) bv = bias[col];
    #pragma unroll
    for (int i = 0; i < 4; ++i) {
      #pragma unroll
      for (int r = 0; r < 4; ++r) {
        const int row = m0 + wr + i * 16 + lg * 4 + r;
        float v = acc[i][j][r] + bv;
        if constexpr (SK == 1 && EPI == 1) v = fmaxf(v, 0.f);
        if constexpr (sizeof(OutT) == 2) C[(size_t)row * N + col] = f2bf(v);
        else                             C[(size_t)row * N + col] = v;
      }
    }
  }
}

// ---------------------------------------------------------------- causal flash attention
// Paired q-tiles (p, 31-p); V column XOR-swizzle; DPP softmax reductions;
// Q pre-scaled by 1/8 (exact in bf16); setprio around MFMA clusters.
// kqv: (B*S, 3E) bf16, row = [K | Q | V], each section col = h*64 + d
__global__ __launch_bounds__(256) void attn_kernel(
    const short* __restrict__ kqv, short* __restrict__ out)
{
  __shared__ short Kt[64][72];        // K rows (k) x d
  __shared__ short Vt[64][72];        // transposed: d x k, col k XOR-swizzled by 8*((d>>3)&7)
  __shared__ short Pl[4][16][72];     // per-wave P tile

  const int tid = threadIdx.x, w = tid >> 6, lane = tid & 63;
  const int p = blockIdx.x;           // 0..15
  const int bh = blockIdx.y;          // 0..31
  const int b = bh >> 4, h = bh & 15;
  const int q0lo = p << 6, q0hi = (31 - p) << 6;
  const int nkb = 32 - p;             // k-blocks for the hi tile
  const int lr = lane & 15, lg = lane >> 4;

  // Q fragments: rows q0 + w*16 + lr, d = ks*32 + lg*8 ..+8; pre-scaled by 1/8 (exact)
  const size_t rowlo = (size_t)(b * S_ + q0lo + w * 16 + lr) * 3072 + 1024 + h * 64;
  const size_t rowhi = (size_t)(b * S_ + q0hi + w * 16 + lr) * 3072 + 1024 + h * 64;
  bf16x8 qlo[2], qhi[2];
  qlo[0] = *(const bf16x8*)&kqv[rowlo + lg * 8];
  qlo[1] = *(const bf16x8*)&kqv[rowlo + 32 + lg * 8];
  qhi[0] = *(const bf16x8*)&kqv[rowhi + lg * 8];
  qhi[1] = *(const bf16x8*)&kqv[rowhi + 32 + lg * 8];
  #pragma unroll
  for (int ks = 0; ks < 2; ++ks)
    #pragma unroll
    for (int e = 0; e < 8; ++e) {
      qlo[ks][e] = f2bf(bf2f(qlo[ks][e]) * 0.125f);
      qhi[ks][e] = f2bf(bf2f(qhi[ks][e]) * 0.125f);
    }

  f32x4 aclo[4] = {}, achi[4] = {};
  float mlo[4], llo[4], mhi[4], lhi[4];
  #pragma unroll
  for (int r = 0; r < 4; ++r) { mlo[r] = mhi[r] = -1e30f; llo[r] = lhi[r] = 0.f; }

  const int skk = tid >> 3;           // 0..31 staging row (k)
  const int sc  = (tid & 7) << 3;     // staging col (d)
  const int vws = (tid & 7) << 3;     // V write swizzle: 8*((sc+e)>>3 & 7) = 8*(tid&7)

  for (int kbi = 0; kbi < nkb; ++kbi) {
    const int kb = kbi << 6;
    // ---- stage K (row-major) and V (transposed, col-swizzled) into LDS
    #pragma unroll
    for (int i = 0; i < 2; ++i) {
      const int krow = skk + i * 32;
      const size_t gb = (size_t)(b * S_ + kb + krow) * 3072 + h * 64 + sc;
      *(bf16x8*)&Kt[krow][sc] = *(const bf16x8*)&kqv[gb];          // c=0: K
      bf16x8 vv = *(const bf16x8*)&kqv[gb + 2048];                  // c=2: V
      const int kc = krow ^ vws;
      #pragma unroll
      for (int e = 0; e < 8; ++e) Vt[sc + e][kc] = vv[e];
    }
    __syncthreads();

    // ---- per-tile processing
    auto process = [&](const bf16x8 (&qf)[2], f32x4 (&acc)[4],
                       float (&m_run)[4], float (&l_run)[4], int q0) {
      // S = Q K^T  (per wave: 16 q rows x 64 k cols)
      f32x4 sacc[4] = {};
      __builtin_amdgcn_s_setprio(1);
      #pragma unroll
      for (int jt = 0; jt < 4; ++jt) {
        #pragma unroll
        for (int ks = 0; ks < 2; ++ks) {
          bf16x8 kf = *(const bf16x8*)&Kt[jt * 16 + lr][ks * 32 + lg * 8];
          sacc[jt] = MFMA16(qf[ks], kf, sacc[jt]);
        }
      }
      __builtin_amdgcn_s_setprio(0);
      // causal mask + row max (scale already folded into Q)
      float rmax[4];
      #pragma unroll
      for (int r = 0; r < 4; ++r) rmax[r] = -1e30f;
      #pragma unroll
      for (int jt = 0; jt < 4; ++jt) {
        const int kpos = kb + jt * 16 + lr;
        #pragma unroll
        for (int r = 0; r < 4; ++r) {
          const int qrow = q0 + w * 16 + lg * 4 + r;
          float v = sacc[jt][r];
          v = (kpos <= qrow) ? v : -1e30f;
          sacc[jt][r] = v;
          rmax[r] = fmaxf(rmax[r], v);
        }
      }
      #pragma unroll
      for (int r = 0; r < 4; ++r) rmax[r] = dpp_max16(rmax[r]);
      // online softmax update
      float alpha[4], rsum[4];
      #pragma unroll
      for (int r = 0; r < 4; ++r) {
        float mn = fmaxf(m_run[r], rmax[r]);
        alpha[r] = __expf(m_run[r] - mn);
        m_run[r] = mn;
        rsum[r] = 0.f;
      }
      #pragma unroll
      for (int jt = 0; jt < 4; ++jt)
        #pragma unroll
        for (int r = 0; r < 4; ++r) {
          float pv = __expf(sacc[jt][r] - m_run[r]);
          sacc[jt][r] = pv;
          rsum[r] += pv;
        }
      #pragma unroll
      for (int r = 0; r < 4; ++r) rsum[r] = dpp_sum16(rsum[r]);
      #pragma unroll
      for (int r = 0; r < 4; ++r) l_run[r] = l_run[r] * alpha[r] + rsum[r];
      #pragma unroll
      for (int dt = 0; dt < 4; ++dt)
        #pragma unroll
        for (int r = 0; r < 4; ++r) acc[dt][r] *= alpha[r];
      // P -> LDS (bf16), then PV
      #pragma unroll
      for (int jt = 0; jt < 4; ++jt)
        #pragma unroll
        for (int r = 0; r < 4; ++r)
          Pl[w][lg * 4 + r][jt * 16 + lr] = f2bf(sacc[jt][r]);
      bf16x8 pa[2];
      pa[0] = *(const bf16x8*)&Pl[w][lr][lg * 8];
      pa[1] = *(const bf16x8*)&Pl[w][lr][32 + lg * 8];
      __builtin_amdgcn_s_setprio(1);
      #pragma unroll
      for (int dt = 0; dt < 4; ++dt) {
        const int vswz = (2 * dt + (lr >> 3)) << 3;   // 8*((row>>3)&7), row = dt*16+lr
        #pragma unroll
        for (int ks = 0; ks < 2; ++ks) {
          bf16x8 vb = *(const bf16x8*)&Vt[dt * 16 + lr][(ks * 32 + lg * 8) ^ vswz];
          acc[dt] = MFMA16(pa[ks], vb, acc[dt]);
        }
      }
      __builtin_amdgcn_s_setprio(0);
    };

    process(qhi, achi, mhi, lhi, q0hi);
    if (kb <= q0lo + w * 16 + 15) process(qlo, aclo, mlo, llo, q0lo);
    __syncthreads();
  }

  // ---- epilogue: normalize and store both tiles
  #pragma unroll
  for (int dt = 0; dt < 4; ++dt) {
    #pragma unroll
    for (int r = 0; r < 4; ++r) {
      const int d = h * 64 + dt * 16 + lr;
      const int qlo_row = q0lo + w * 16 + lg * 4 + r;
      const int qhi_row = q0hi + w * 16 + lg * 4 + r;
      out[(size_t)(b * S_ + qlo_row) * E_ + d] = f2bf(aclo[dt][r] / llo[r]);
      out[(size_t)(b * S_ + qhi_row) * E_ + d] = f2bf(achi[dt][r] / lhi[r]);
    }
  }
}

// ---------------------------------------------------------------- residual + LayerNorm (split-K fold)
// FINAL=0: r = y0 + y1 + res(f32)            -> LN(g,b) -> out bf16
// FINAL=1: r = y0 + y1 + bias + res(bf16)    -> LN(g,b) -> out f32
template<int FINAL>
__global__ __launch_bounds__(256) void ln_kernel(
    const float* __restrict__ y0, const float* __restrict__ y1,
    const float* __restrict__ bias, const void* __restrict__ res,
    const float* __restrict__ gam, const float* __restrict__ bet,
    void* __restrict__ outp)
{
  const int row = blockIdx.x, tid = threadIdx.x, lane = tid & 63, w = tid >> 6;
  float4 a = ((const float4*)(y0 + (size_t)row * E_))[tid];
  float4 c = ((const float4*)(y1 + (size_t)row * E_))[tid];
  float r[4] = {a.x + c.x, a.y + c.y, a.z + c.z, a.w + c.w};
  if constexpr (FINAL) {
    float4 bi = ((const float4*)bias)[tid];
    shortx4 rb = ((const shortx4*)((const short*)res + (size_t)row * E_))[tid];
    r[0] += bi.x + bf2f(rb.x); r[1] += bi.y + bf2f(rb.y);
    r[2] += bi.z + bf2f(rb.z); r[3] += bi.w + bf2f(rb.w);
  } else {
    float4 rv = ((const float4*)((const float*)res + (size_t)row * E_))[tid];
    r[0] += rv.x; r[1] += rv.y; r[2] += rv.z; r[3] += rv.w;
  }
  float s  = r[0] + r[1] + r[2] + r[3];
  float ss = r[0]*r[0] + r[1]*r[1] + r[2]*r[2] + r[3]*r[3];
  #pragma unroll
  for (int m = 32; m >= 1; m >>= 1) { s += __shfl_xor(s, m); ss += __shfl_xor(ss, m); }
  __shared__ float red[8];
  if (lane == 0) { red[w] = s; red[4 + w] = ss; }
  __syncthreads();
  s  = red[0] + red[1] + red[2] + red[3];
  ss = red[4] + red[5] + red[6] + red[7];
  const float mu  = s * (1.f / E_);
  const float var = ss * (1.f / E_) - mu * mu;
  const float rs  = rsqrtf(var + 1e-6f);
  float4 gv = ((const float4*)gam)[tid];
  float4 bv = ((const float4*)bet)[tid];
  float o0 = (r[0] - mu) * rs * gv.x + bv.x;
  float o1 = (r[1] - mu) * rs * gv.y + bv.y;
  float o2 = (r[2] - mu) * rs * gv.z + bv.z;
  float o3 = (r[3] - mu) * rs * gv.w + bv.w;
  if constexpr (FINAL) {
    float4 o; o.x = o0; o.y = o1; o.z = o2; o.w = o3;
    ((float4*)((float*)outp + (size_t)row * E_))[tid] = o;
  } else {
    shortx4 o; o.x = f2bf(o0); o.y = f2bf(o1); o.z = f2bf(o2); o.w = f2bf(o3);
    ((shortx4*)((short*)outp + (size_t)row * E_))[tid] = o;
  }
}

// ---------------------------------------------------------------- launch
// ws timeline (MB): [0-8 xb][8-14 wkqvb][14-16 wob][16-24 wupb][24-32 wdownb]
//   [32-56 kqv] -> attn writes [64-72 attno] -> proj writes [32-48 proj0][48-64 proj1]
//   -> ln0 writes [72-80 xln] -> up writes [32-64 hbuf]
//   -> down writes [0-16 down0][80-96 down1] -> ln1.  Peak 96 MB (validated).
extern "C" void kernel_launch(void* const* d_in, const int* in_sizes, int n_in,
                              void* d_out, int out_size, void* d_ws, size_t ws_size,
                              hipStream_t stream) {
  const float* x      = (const float*)d_in[0];
  const float* w_kqv  = (const float*)d_in[2];
  const float* w_o    = (const float*)d_in[3];
  const float* w_up   = (const float*)d_in[4];
  const float* b_up   = (const float*)d_in[5];
  const float* w_down = (const float*)d_in[6];
  const float* b_down = (const float*)d_in[7];
  const float* g1     = (const float*)d_in[8];
  const float* b1     = (const float*)d_in[9];
  const float* g2     = (const float*)d_in[10];
  const float* b2     = (const float*)d_in[11];
  float* out = (float*)d_out;

  char* ws = (char*)d_ws;
  short* xb     = (short*)(ws);
  short* wkqvb  = (short*)(ws + ((size_t)8  << 20));
  short* wob    = (short*)(ws + ((size_t)14 << 20));
  short* wupb   = (short*)(ws + ((size_t)16 << 20));
  short* wdownb = (short*)(ws + ((size_t)24 << 20));
  short* kqv    = (short*)(ws + ((size_t)32 << 20));
  float* proj0  = (float*)(ws + ((size_t)32 << 20));
  float* proj1  = (float*)(ws + ((size_t)48 << 20));
  short* hbuf   = (short*)(ws + ((size_t)32 << 20));
  short* attno  = (short*)(ws + ((size_t)64 << 20));
  short* xln    = (short*)(ws + ((size_t)72 << 20));
  float* down0  = (float*)(ws);
  float* down1  = (float*)(ws + ((size_t)80 << 20));

  cast_all<<<2048, 256, 0, stream>>>(x, w_kqv, w_o, w_up, w_down,
                                     xb, wkqvb, wob, wupb, wdownb);

  gemm_bt<1, 0, short><<<24 * 32, 256, 0, stream>>>(xb, wkqvb, kqv, nullptr, nullptr, M_, 3 * E_, E_);
  attn_kernel<<<dim3(16, B_ * H_), 256, 0, stream>>>(kqv, attno);
  gemm_bt<2, 0, float><<<dim3(256, 2), 256, 0, stream>>>(attno, wob, proj0, proj1, nullptr, M_, E_, E_);
  ln_kernel<0><<<M_, 256, 0, stream>>>(proj0, proj1, nullptr, x, g1, b1, xln);
  gemm_bt<1, 1, short><<<32 * 32, 256, 0, stream>>>(xln, wupb, hbuf, nullptr, b_up, M_, FF_, E_);
  gemm_bt<2, 0, float><<<dim3(256, 2), 256, 0, stream>>>(hbuf, wdownb, down0, down1, nullptr, M_, E_, FF_);
  ln_kernel<1><<<M_, 256, 0, stream>>>(down0, down1, b_down, xln, g2, b2, out);
}

// Round 7
// 277.201 us; speedup vs baseline: 1.4756x; 1.0002x over previous
//
#include <hip/hip_runtime.h>
#include <stdint.h>

#define B_ 2
#define S_ 2048
#define E_ 1024
#define H_ 16
#define HD_ 64
#define FF_ 4096
#define M_ 4096   // B*S
#define LOG2E_ 1.44269504f

typedef short bf16x8 __attribute__((ext_vector_type(8)));
typedef float f32x4  __attribute__((ext_vector_type(4)));
typedef short shortx4 __attribute__((ext_vector_type(4)));

#define MFMA16(a,b,c) __builtin_amdgcn_mfma_f32_16x16x32_bf16(a,b,c,0,0,0)

__device__ __forceinline__ short f2bf(float f) {
  uint32_t u = __builtin_bit_cast(uint32_t, f);
  u += 0x7fffu + ((u >> 16) & 1u);
  return (short)(u >> 16);
}
__device__ __forceinline__ float bf2f(short b) {
  uint32_t u = ((uint32_t)(uint16_t)b) << 16;
  return __builtin_bit_cast(float, u);
}
__device__ __forceinline__ float exp2_hw(float x) {
  float r;
  asm("v_exp_f32 %0, %1" : "=v"(r) : "v"(x));
  return r;
}

// DPP row-rotate (16-lane row), VALU-pipe cross-lane: ROW_ROR:N = 0x120|N
template<int CTRL>
__device__ __forceinline__ float dpp_ror(float x) {
  return __builtin_bit_cast(float,
    __builtin_amdgcn_update_dpp(0, __builtin_bit_cast(int, x), CTRL, 0xF, 0xF, true));
}
__device__ __forceinline__ float dpp_max16(float v) {
  v = fmaxf(v, dpp_ror<0x128>(v));
  v = fmaxf(v, dpp_ror<0x124>(v));
  v = fmaxf(v, dpp_ror<0x122>(v));
  v = fmaxf(v, dpp_ror<0x121>(v));
  return v;
}
__device__ __forceinline__ float dpp_sum16(float v) {
  v += dpp_ror<0x128>(v);
  v += dpp_ror<0x124>(v);
  v += dpp_ror<0x122>(v);
  v += dpp_ror<0x121>(v);
  return v;
}

// async global->LDS, 16B per lane, wave-uniform LDS base + lane*16 (per-lane global src)
#define GLDS16(g, l) __builtin_amdgcn_global_load_lds( \
    (const __attribute__((address_space(1))) unsigned int*)(g), \
    (__attribute__((address_space(3))) unsigned int*)(l), 16, 0, 0)

// ---------------------------------------------------------------- fused cast f32->bf16 (all 5 arrays)
__global__ void cast_all(const float* __restrict__ x, const float* __restrict__ wkqv,
                         const float* __restrict__ wo, const float* __restrict__ wup,
                         const float* __restrict__ wdown,
                         short* __restrict__ xb, short* __restrict__ wkqvb,
                         short* __restrict__ wob, short* __restrict__ wupb,
                         short* __restrict__ wdownb) {
  const int stride = gridDim.x * blockDim.x;
  for (int i = blockIdx.x * blockDim.x + threadIdx.x; i < 4194304; i += stride) {
    const int e = i << 2;
    const float* src; short* dst; int off;
    if (e < 4194304)       { src = x;     dst = xb;     off = e; }
    else if (e < 7340032)  { src = wkqv;  dst = wkqvb;  off = e - 4194304; }
    else if (e < 8388608)  { src = wo;    dst = wob;    off = e - 7340032; }
    else if (e < 12582912) { src = wup;   dst = wupb;   off = e - 8388608; }
    else                   { src = wdown; dst = wdownb; off = e - 12582912; }
    float4 v = *(const float4*)(src + off);
    shortx4 o;
    o.x = f2bf(v.x); o.y = f2bf(v.y); o.z = f2bf(v.z); o.w = f2bf(v.w);
    *(shortx4*)(dst + off) = o;
  }
}

// ---------------------------------------------------------------- GEMM  C = A * Bw^T
// A: M x K bf16 row-major.  Bw: N x K bf16 row-major.  m97 structure, BM=128.
// SK: split-K factor. SK=1: C0 with EPI epilogue. SK=2: y-slice s writes partial
// (s==0 ? C0 : C1), EPI ignored (bias folded downstream).
template<int SK, int EPI, typename OutT>
__global__ __launch_bounds__(256) void gemm_bt(
    const short* __restrict__ A, const short* __restrict__ Bw,
    OutT* __restrict__ C0, OutT* __restrict__ C1, const float* __restrict__ bias,
    int M, int N, int K)
{
  __shared__ short Al[128 * 32];
  __shared__ short Bl[128 * 32];
  const int tid  = threadIdx.x;
  const int w    = tid >> 6, lane = tid & 63;
  const int ntiles = N >> 7;
  const int nwg = gridDim.x;
  const int bid = blockIdx.x;
  const int swz = (bid & 7) * (nwg >> 3) + (bid >> 3);
  const int tn = swz % ntiles, tm = swz / ntiles;
  const int m0 = tm << 7, n0 = tn << 7;
  const int wr = (w >> 1) << 6, wc = (w & 1) << 6;
  const int lr = lane & 15, lk = (lane >> 4) << 3;
  const int ra = lane >> 2, colA = (lane & 3) << 3;

  const int kper = K / SK;
  const int kbeg = (SK > 1) ? (int)blockIdx.y * kper : 0;
  const int kend = kbeg + kper;
  OutT* __restrict__ C = (SK > 1 && blockIdx.y) ? C1 : C0;

  f32x4 acc[4][4] = {};

  for (int k0 = kbeg; k0 < kend; k0 += 32) {
    __syncthreads();
    #pragma unroll
    for (int i = 0; i < 2; ++i) {
      const int ch = w + (i << 2);
      GLDS16(A  + (size_t)(m0 + ch * 16 + ra) * K + k0 + colA, &Al[ch * 512]);
      GLDS16(Bw + (size_t)(n0 + ch * 16 + ra) * K + k0 + colA, &Bl[ch * 512]);
    }
    __syncthreads();
    bf16x8 af[4], bfr[4];
    #pragma unroll
    for (int i = 0; i < 4; ++i)
      af[i] = *(const bf16x8*)&Al[(wr + i * 16 + lr) * 32 + lk];
    #pragma unroll
    for (int j = 0; j < 4; ++j)
      bfr[j] = *(const bf16x8*)&Bl[(wc + j * 16 + lr) * 32 + lk];
    #pragma unroll
    for (int i = 0; i < 4; ++i)
      #pragma unroll
      for (int j = 0; j < 4; ++j)
        acc[i][j] = MFMA16(af[i], bfr[j], acc[i][j]);
  }

  const int lg = lane >> 4;
  #pragma unroll
  for (int j = 0; j < 4; ++j) {
    const int col = n0 + wc + j * 16 + lr;
    float bv = 0.f;
    if constexpr (SK == 1 && EPI != 0) bv = bias[col];
    #pragma unroll
    for (int i = 0; i < 4; ++i) {
      #pragma unroll
      for (int r = 0; r < 4; ++r) {
        const int row = m0 + wr + i * 16 + lg * 4 + r;
        float v = acc[i][j][r] + bv;
        if constexpr (SK == 1 && EPI == 1) v = fmaxf(v, 0.f);
        if constexpr (sizeof(OutT) == 2) C[(size_t)row * N + col] = f2bf(v);
        else                             C[(size_t)row * N + col] = v;
      }
    }
  }
}

// ---------------------------------------------------------------- causal flash attention
// Paired q-tiles (p, 31-p); V column XOR-swizzle; DPP softmax reductions;
// Q pre-scaled by 1/8 (exact); full-tile mask skip; defer-max (THR=8);
// exp2-domain softmax; cvt_pk P-write; setprio around MFMA clusters.
__global__ __launch_bounds__(256) void attn_kernel(
    const short* __restrict__ kqv, short* __restrict__ out)
{
  __shared__ short Kt[64][72];        // K rows (k) x d
  __shared__ short Vt[64][72];        // transposed: d x k, col k XOR-swizzled by 8*((d>>3)&7)
  __shared__ short Pl[4][16][72];     // per-wave P tile

  const int tid = threadIdx.x, w = tid >> 6, lane = tid & 63;
  const int p = blockIdx.x;           // 0..15
  const int bh = blockIdx.y;          // 0..31
  const int b = bh >> 4, h = bh & 15;
  const int q0lo = p << 6, q0hi = (31 - p) << 6;
  const int nkb = 32 - p;             // k-blocks for the hi tile
  const int lr = lane & 15, lg = lane >> 4;

  // Q fragments: rows q0 + w*16 + lr, d = ks*32 + lg*8 ..+8; pre-scaled by 1/8 (exact)
  const size_t rowlo = (size_t)(b * S_ + q0lo + w * 16 + lr) * 3072 + 1024 + h * 64;
  const size_t rowhi = (size_t)(b * S_ + q0hi + w * 16 + lr) * 3072 + 1024 + h * 64;
  bf16x8 qlo[2], qhi[2];
  qlo[0] = *(const bf16x8*)&kqv[rowlo + lg * 8];
  qlo[1] = *(const bf16x8*)&kqv[rowlo + 32 + lg * 8];
  qhi[0] = *(const bf16x8*)&kqv[rowhi + lg * 8];
  qhi[1] = *(const bf16x8*)&kqv[rowhi + 32 + lg * 8];
  #pragma unroll
  for (int ks = 0; ks < 2; ++ks)
    #pragma unroll
    for (int e = 0; e < 8; ++e) {
      qlo[ks][e] = f2bf(bf2f(qlo[ks][e]) * 0.125f);
      qhi[ks][e] = f2bf(bf2f(qhi[ks][e]) * 0.125f);
    }

  f32x4 aclo[4] = {}, achi[4] = {};
  float mlo[4], llo[4], mhi[4], lhi[4];
  #pragma unroll
  for (int r = 0; r < 4; ++r) { mlo[r] = mhi[r] = -1e30f; llo[r] = lhi[r] = 0.f; }

  const int skk = tid >> 3;           // 0..31 staging row (k)
  const int sc  = (tid & 7) << 3;     // staging col (d)
  const int vws = (tid & 7) << 3;     // V write swizzle: 8*((sc+e)>>3 & 7) = 8*(tid&7)

  for (int kbi = 0; kbi < nkb; ++kbi) {
    const int kb = kbi << 6;
    // ---- stage K (row-major) and V (transposed, col-swizzled) into LDS
    #pragma unroll
    for (int i = 0; i < 2; ++i) {
      const int krow = skk + i * 32;
      const size_t gb = (size_t)(b * S_ + kb + krow) * 3072 + h * 64 + sc;
      *(bf16x8*)&Kt[krow][sc] = *(const bf16x8*)&kqv[gb];          // c=0: K
      bf16x8 vv = *(const bf16x8*)&kqv[gb + 2048];                  // c=2: V
      const int kc = krow ^ vws;
      #pragma unroll
      for (int e = 0; e < 8; ++e) Vt[sc + e][kc] = vv[e];
    }
    __syncthreads();

    // ---- per-tile processing
    auto process = [&](const bf16x8 (&qf)[2], f32x4 (&acc)[4],
                       float (&m_run)[4], float (&l_run)[4], int q0) {
      // S = Q K^T  (per wave: 16 q rows x 64 k cols)
      f32x4 sacc[4] = {};
      __builtin_amdgcn_s_setprio(1);
      #pragma unroll
      for (int jt = 0; jt < 4; ++jt) {
        #pragma unroll
        for (int ks = 0; ks < 2; ++ks) {
          bf16x8 kf = *(const bf16x8*)&Kt[jt * 16 + lr][ks * 32 + lg * 8];
          sacc[jt] = MFMA16(qf[ks], kf, sacc[jt]);
        }
      }
      __builtin_amdgcn_s_setprio(0);
      // row max; skip causal mask on full tiles (wave-uniform)
      const bool full = (kb + 63 <= q0 + w * 16);
      float rmax[4];
      if (full) {
        #pragma unroll
        for (int r = 0; r < 4; ++r)
          rmax[r] = fmaxf(fmaxf(sacc[0][r], sacc[1][r]), fmaxf(sacc[2][r], sacc[3][r]));
      } else {
        #pragma unroll
        for (int r = 0; r < 4; ++r) rmax[r] = -1e30f;
        #pragma unroll
        for (int jt = 0; jt < 4; ++jt) {
          const int kpos = kb + jt * 16 + lr;
          #pragma unroll
          for (int r = 0; r < 4; ++r) {
            const int qrow = q0 + w * 16 + lg * 4 + r;
            float v = (kpos <= qrow) ? sacc[jt][r] : -1e30f;
            sacc[jt][r] = v;
            rmax[r] = fmaxf(rmax[r], v);
          }
        }
      }
      #pragma unroll
      for (int r = 0; r < 4; ++r) rmax[r] = dpp_max16(rmax[r]);
      // defer-max: rescale only when max grew by > 8 (wave-uniform vote)
      int need = 0;
      #pragma unroll
      for (int r = 0; r < 4; ++r) need |= (rmax[r] > m_run[r] + 8.f) ? 1 : 0;
      if (__any(need)) {
        #pragma unroll
        for (int r = 0; r < 4; ++r) {
          const float mn = fmaxf(m_run[r], rmax[r]);
          const float al = exp2_hw((m_run[r] - mn) * LOG2E_);
          m_run[r] = mn;
          l_run[r] *= al;
          #pragma unroll
          for (int dt = 0; dt < 4; ++dt) acc[dt][r] *= al;
        }
      }
      // exp2-domain softmax: pv = 2^(s*log2e - m*log2e)
      float m2[4], rsum[4];
      #pragma unroll
      for (int r = 0; r < 4; ++r) { m2[r] = m_run[r] * LOG2E_; rsum[r] = 0.f; }
      #pragma unroll
      for (int jt = 0; jt < 4; ++jt)
        #pragma unroll
        for (int r = 0; r < 4; ++r) {
          const float pv = exp2_hw(__builtin_fmaf(sacc[jt][r], LOG2E_, -m2[r]));
          sacc[jt][r] = pv;
          rsum[r] += pv;
        }
      #pragma unroll
      for (int r = 0; r < 4; ++r) { rsum[r] = dpp_sum16(rsum[r]); l_run[r] += rsum[r]; }
      // P -> LDS via v_cvt_pk_bf16_f32 (S0 -> lo, S1 -> hi), q-pairs adjacent in regs
      #pragma unroll
      for (int jt = 0; jt < 4; ++jt) {
        uint32_t w01, w23;
        asm("v_cvt_pk_bf16_f32 %0, %1, %2" : "=v"(w01) : "v"(sacc[jt][0]), "v"(sacc[jt][1]));
        asm("v_cvt_pk_bf16_f32 %0, %1, %2" : "=v"(w23) : "v"(sacc[jt][2]), "v"(sacc[jt][3]));
        Pl[w][lg * 4 + 0][jt * 16 + lr] = (short)(w01 & 0xffffu);
        Pl[w][lg * 4 + 1][jt * 16 + lr] = (short)(w01 >> 16);
        Pl[w][lg * 4 + 2][jt * 16 + lr] = (short)(w23 & 0xffffu);
        Pl[w][lg * 4 + 3][jt * 16 + lr] = (short)(w23 >> 16);
      }
      bf16x8 pa[2];
      pa[0] = *(const bf16x8*)&Pl[w][lr][lg * 8];
      pa[1] = *(const bf16x8*)&Pl[w][lr][32 + lg * 8];
      __builtin_amdgcn_s_setprio(1);
      #pragma unroll
      for (int dt = 0; dt < 4; ++dt) {
        const int vswz = (2 * dt + (lr >> 3)) << 3;   // 8*((row>>3)&7), row = dt*16+lr
        #pragma unroll
        for (int ks = 0; ks < 2; ++ks) {
          bf16x8 vb = *(const bf16x8*)&Vt[dt * 16 + lr][(ks * 32 + lg * 8) ^ vswz];
          acc[dt] = MFMA16(pa[ks], vb, acc[dt]);
        }
      }
      __builtin_amdgcn_s_setprio(0);
    };

    process(qhi, achi, mhi, lhi, q0hi);
    if (kb <= q0lo + w * 16 + 15) process(qlo, aclo, mlo, llo, q0lo);
    __syncthreads();
  }

  // ---- epilogue: normalize and store both tiles
  #pragma unroll
  for (int dt = 0; dt < 4; ++dt) {
    #pragma unroll
    for (int r = 0; r < 4; ++r) {
      const int d = h * 64 + dt * 16 + lr;
      const int qlo_row = q0lo + w * 16 + lg * 4 + r;
      const int qhi_row = q0hi + w * 16 + lg * 4 + r;
      out[(size_t)(b * S_ + qlo_row) * E_ + d] = f2bf(aclo[dt][r] / llo[r]);
      out[(size_t)(b * S_ + qhi_row) * E_ + d] = f2bf(achi[dt][r] / lhi[r]);
    }
  }
}

// ---------------------------------------------------------------- residual + LayerNorm (split-K fold)
template<int FINAL>
__global__ __launch_bounds__(256) void ln_kernel(
    const float* __restrict__ y0, const float* __restrict__ y1,
    const float* __restrict__ bias, const void* __restrict__ res,
    const float* __restrict__ gam, const float* __restrict__ bet,
    void* __restrict__ outp)
{
  const int row = blockIdx.x, tid = threadIdx.x, lane = tid & 63, w = tid >> 6;
  float4 a = ((const float4*)(y0 + (size_t)row * E_))[tid];
  float4 c = ((const float4*)(y1 + (size_t)row * E_))[tid];
  float r[4] = {a.x + c.x, a.y + c.y, a.z + c.z, a.w + c.w};
  if constexpr (FINAL) {
    float4 bi = ((const float4*)bias)[tid];
    shortx4 rb = ((const shortx4*)((const short*)res + (size_t)row * E_))[tid];
    r[0] += bi.x + bf2f(rb.x); r[1] += bi.y + bf2f(rb.y);
    r[2] += bi.z + bf2f(rb.z); r[3] += bi.w + bf2f(rb.w);
  } else {
    float4 rv = ((const float4*)((const float*)res + (size_t)row * E_))[tid];
    r[0] += rv.x; r[1] += rv.y; r[2] += rv.z; r[3] += rv.w;
  }
  float s  = r[0] + r[1] + r[2] + r[3];
  float ss = r[0]*r[0] + r[1]*r[1] + r[2]*r[2] + r[3]*r[3];
  #pragma unroll
  for (int m = 32; m >= 1; m >>= 1) { s += __shfl_xor(s, m); ss += __shfl_xor(ss, m); }
  __shared__ float red[8];
  if (lane == 0) { red[w] = s; red[4 + w] = ss; }
  __syncthreads();
  s  = red[0] + red[1] + red[2] + red[3];
  ss = red[4] + red[5] + red[6] + red[7];
  const float mu  = s * (1.f / E_);
  const float var = ss * (1.f / E_) - mu * mu;
  const float rs  = rsqrtf(var + 1e-6f);
  float4 gv = ((const float4*)gam)[tid];
  float4 bv = ((const float4*)bet)[tid];
  float o0 = (r[0] - mu) * rs * gv.x + bv.x;
  float o1 = (r[1] - mu) * rs * gv.y + bv.y;
  float o2 = (r[2] - mu) * rs * gv.z + bv.z;
  float o3 = (r[3] - mu) * rs * gv.w + bv.w;
  if constexpr (FINAL) {
    float4 o; o.x = o0; o.y = o1; o.z = o2; o.w = o3;
    ((float4*)((float*)outp + (size_t)row * E_))[tid] = o;
  } else {
    shortx4 o; o.x = f2bf(o0); o.y = f2bf(o1); o.z = f2bf(o2); o.w = f2bf(o3);
    ((shortx4*)((short*)outp + (size_t)row * E_))[tid] = o;
  }
}

// ---------------------------------------------------------------- launch
// ws timeline (MB): [0-8 xb][8-14 wkqvb][14-16 wob][16-24 wupb][24-32 wdownb]
//   [32-56 kqv] -> attn [64-72 attno] -> proj [32-48 p0][48-64 p1] -> ln0 [72-80 xln]
//   -> up [32-64 hbuf] -> down [0-16 d0][80-96 d1] -> ln1.  Peak 96 MB.
extern "C" void kernel_launch(void* const* d_in, const int* in_sizes, int n_in,
                              void* d_out, int out_size, void* d_ws, size_t ws_size,
                              hipStream_t stream) {
  const float* x      = (const float*)d_in[0];
  const float* w_kqv  = (const float*)d_in[2];
  const float* w_o    = (const float*)d_in[3];
  const float* w_up   = (const float*)d_in[4];
  const float* b_up   = (const float*)d_in[5];
  const float* w_down = (const float*)d_in[6];
  const float* b_down = (const float*)d_in[7];
  const float* g1     = (const float*)d_in[8];
  const float* b1     = (const float*)d_in[9];
  const float* g2     = (const float*)d_in[10];
  const float* b2     = (const float*)d_in[11];
  float* out = (float*)d_out;

  char* ws = (char*)d_ws;
  short* xb     = (short*)(ws);
  short* wkqvb  = (short*)(ws + ((size_t)8  << 20));
  short* wob    = (short*)(ws + ((size_t)14 << 20));
  short* wupb   = (short*)(ws + ((size_t)16 << 20));
  short* wdownb = (short*)(ws + ((size_t)24 << 20));
  short* kqv    = (short*)(ws + ((size_t)32 << 20));
  float* proj0  = (float*)(ws + ((size_t)32 << 20));
  float* proj1  = (float*)(ws + ((size_t)48 << 20));
  short* hbuf   = (short*)(ws + ((size_t)32 << 20));
  short* attno  = (short*)(ws + ((size_t)64 << 20));
  short* xln    = (short*)(ws + ((size_t)72 << 20));
  float* down0  = (float*)(ws);
  float* down1  = (float*)(ws + ((size_t)80 << 20));

  cast_all<<<2048, 256, 0, stream>>>(x, w_kqv, w_o, w_up, w_down,
                                     xb, wkqvb, wob, wupb, wdownb);

  gemm_bt<1, 0, short><<<24 * 32, 256, 0, stream>>>(xb, wkqvb, kqv, nullptr, nullptr, M_, 3 * E_, E_);
  attn_kernel<<<dim3(16, B_ * H_), 256, 0, stream>>>(kqv, attno);
  gemm_bt<2, 0, float><<<dim3(256, 2), 256, 0, stream>>>(attno, wob, proj0, proj1, nullptr, M_, E_, E_);
  ln_kernel<0><<<M_, 256, 0, stream>>>(proj0, proj1, nullptr, x, g1, b1, xln);
  gemm_bt<1, 1, short><<<32 * 32, 256, 0, stream>>>(xln, wupb, hbuf, nullptr, b_up, M_, FF_, E_);
  gemm_bt<2, 0, float><<<dim3(256, 2), 256, 0, stream>>>(hbuf, wdownb, down0, down1, nullptr, M_, E_, FF_);
  ln_kernel<1><<<M_, 256, 0, stream>>>(down0, down1, b_down, xln, g2, b2, out);
}

// Round 8
// 257.444 us; speedup vs baseline: 1.5889x; 1.0767x over previous
//
#include <hip/hip_runtime.h>
#include <stdint.h>

#define B_ 2
#define S_ 2048
#define E_ 1024
#define H_ 16
#define HD_ 64
#define FF_ 4096
#define M_ 4096   // B*S
#define LOG2E_ 1.44269504f

typedef short bf16x8 __attribute__((ext_vector_type(8)));
typedef float f32x4  __attribute__((ext_vector_type(4)));
typedef short shortx4 __attribute__((ext_vector_type(4)));

#define MFMA16(a,b,c) __builtin_amdgcn_mfma_f32_16x16x32_bf16(a,b,c,0,0,0)

__device__ __forceinline__ short f2bf(float f) {
  uint32_t u = __builtin_bit_cast(uint32_t, f);
  u += 0x7fffu + ((u >> 16) & 1u);
  return (short)(u >> 16);
}
__device__ __forceinline__ float bf2f(short b) {
  uint32_t u = ((uint32_t)(uint16_t)b) << 16;
  return __builtin_bit_cast(float, u);
}
__device__ __forceinline__ float exp2_hw(float x) {
  float r;
  asm("v_exp_f32 %0, %1" : "=v"(r) : "v"(x));
  return r;
}

// DPP row-rotate (16-lane row), VALU-pipe cross-lane: ROW_ROR:N = 0x120|N
template<int CTRL>
__device__ __forceinline__ float dpp_ror(float x) {
  return __builtin_bit_cast(float,
    __builtin_amdgcn_update_dpp(0, __builtin_bit_cast(int, x), CTRL, 0xF, 0xF, true));
}
__device__ __forceinline__ float dpp_max16(float v) {
  v = fmaxf(v, dpp_ror<0x128>(v));
  v = fmaxf(v, dpp_ror<0x124>(v));
  v = fmaxf(v, dpp_ror<0x122>(v));
  v = fmaxf(v, dpp_ror<0x121>(v));
  return v;
}
__device__ __forceinline__ float dpp_sum16(float v) {
  v += dpp_ror<0x128>(v);
  v += dpp_ror<0x124>(v);
  v += dpp_ror<0x122>(v);
  v += dpp_ror<0x121>(v);
  return v;
}

// async global->LDS, 16B per lane, wave-uniform LDS base + lane*16 (per-lane global src)
#define GLDS16(g, l) __builtin_amdgcn_global_load_lds( \
    (const __attribute__((address_space(1))) unsigned int*)(g), \
    (__attribute__((address_space(3))) unsigned int*)(l), 16, 0, 0)

// ---------------------------------------------------------------- fused cast f32->bf16 (all 5 arrays)
__global__ void cast_all(const float* __restrict__ x, const float* __restrict__ wkqv,
                         const float* __restrict__ wo, const float* __restrict__ wup,
                         const float* __restrict__ wdown,
                         short* __restrict__ xb, short* __restrict__ wkqvb,
                         short* __restrict__ wob, short* __restrict__ wupb,
                         short* __restrict__ wdownb) {
  const int stride = gridDim.x * blockDim.x;
  for (int i = blockIdx.x * blockDim.x + threadIdx.x; i < 4194304; i += stride) {
    const int e = i << 2;
    const float* src; short* dst; int off;
    if (e < 4194304)       { src = x;     dst = xb;     off = e; }
    else if (e < 7340032)  { src = wkqv;  dst = wkqvb;  off = e - 4194304; }
    else if (e < 8388608)  { src = wo;    dst = wob;    off = e - 7340032; }
    else if (e < 12582912) { src = wup;   dst = wupb;   off = e - 8388608; }
    else                   { src = wdown; dst = wdownb; off = e - 12582912; }
    float4 v = *(const float4*)(src + off);
    shortx4 o;
    o.x = f2bf(v.x); o.y = f2bf(v.y); o.z = f2bf(v.z); o.w = f2bf(v.w);
    *(shortx4*)(dst + off) = o;
  }
}

// ---------------------------------------------------------------- GEMM  C = A * Bw^T
// A: M x K bf16 row-major.  Bw: N x K bf16 row-major.  128x128 tile, BK=32.
// 2-phase double-buffered K-loop with counted vmcnt (T3-min + T4):
//   stage(t+1 -> buf^1); vmcnt(4) [tile-t landed]; barrier; ds_read+MFMA(buf);
//   barrier [readers done before t+2 overwrites buf].
// SK: split-K factor. SK=1: C0 with EPI epilogue. SK=2: slice y writes C0/C1.
template<int SK, int EPI, typename OutT>
__global__ __launch_bounds__(256) void gemm_bt(
    const short* __restrict__ A, const short* __restrict__ Bw,
    OutT* __restrict__ C0, OutT* __restrict__ C1, const float* __restrict__ bias,
    int M, int N, int K)
{
  __shared__ short Al[2][128 * 32];
  __shared__ short Bl[2][128 * 32];
  const int tid  = threadIdx.x;
  const int w    = tid >> 6, lane = tid & 63;
  const int ntiles = N >> 7;
  const int nwg = gridDim.x;
  const int bid = blockIdx.x;
  const int swz = (bid & 7) * (nwg >> 3) + (bid >> 3);
  const int tn = swz % ntiles, tm = swz / ntiles;
  const int m0 = tm << 7, n0 = tn << 7;
  const int wr = (w >> 1) << 6, wc = (w & 1) << 6;
  const int lr = lane & 15, lk = (lane >> 4) << 3;
  const int ra = lane >> 2, colA = (lane & 3) << 3;

  const int kper = K / SK;
  const int kbeg = (SK > 1) ? (int)blockIdx.y * kper : 0;
  const int T = kper >> 5;
  OutT* __restrict__ C = (SK > 1 && blockIdx.y) ? C1 : C0;

  // per-wave staging base pointers (chunks ch = w and w+4, 16 rows x 32 cols each)
  const short* Ag0 = A  + (size_t)(m0 + w * 16 + ra) * K + colA;
  const short* Ag1 = A  + (size_t)(m0 + (w + 4) * 16 + ra) * K + colA;
  const short* Bg0 = Bw + (size_t)(n0 + w * 16 + ra) * K + colA;
  const short* Bg1 = Bw + (size_t)(n0 + (w + 4) * 16 + ra) * K + colA;

  f32x4 acc[4][4] = {};

  // prologue: stage tile 0 into buf 0
  {
    const int k0 = kbeg;
    GLDS16(Ag0 + k0, &Al[0][w * 512]);
    GLDS16(Ag1 + k0, &Al[0][(w + 4) * 512]);
    GLDS16(Bg0 + k0, &Bl[0][w * 512]);
    GLDS16(Bg1 + k0, &Bl[0][(w + 4) * 512]);
  }

  for (int it = 0; it < T; ++it) {
    const int buf = it & 1;
    if (it + 1 < T) {
      const int k1 = kbeg + ((it + 1) << 5);
      GLDS16(Ag0 + k1, &Al[buf ^ 1][w * 512]);
      GLDS16(Ag1 + k1, &Al[buf ^ 1][(w + 4) * 512]);
      GLDS16(Bg0 + k1, &Bl[buf ^ 1][w * 512]);
      GLDS16(Bg1 + k1, &Bl[buf ^ 1][(w + 4) * 512]);
      asm volatile("s_waitcnt vmcnt(4)" ::: "memory");
    } else {
      asm volatile("s_waitcnt vmcnt(0)" ::: "memory");
    }
    __builtin_amdgcn_sched_barrier(0);
    __builtin_amdgcn_s_barrier();      // all waves' tile-it loads are in LDS

    bf16x8 af[4], bfr[4];
    #pragma unroll
    for (int i = 0; i < 4; ++i)
      af[i] = *(const bf16x8*)&Al[buf][(wr + i * 16 + lr) * 32 + lk];
    #pragma unroll
    for (int j = 0; j < 4; ++j)
      bfr[j] = *(const bf16x8*)&Bl[buf][(wc + j * 16 + lr) * 32 + lk];
    #pragma unroll
    for (int i = 0; i < 4; ++i)
      #pragma unroll
      for (int j = 0; j < 4; ++j)
        acc[i][j] = MFMA16(af[i], bfr[j], acc[i][j]);

    __builtin_amdgcn_s_barrier();      // readers done before iter it+1 overwrites buf
  }

  const int lg = lane >> 4;
  #pragma unroll
  for (int j = 0; j < 4; ++j) {
    const int col = n0 + wc + j * 16 + lr;
    float bv = 0.f;
    if constexpr (SK == 1 && EPI != 0) bv = bias[col];
    #pragma unroll
    for (int i = 0; i < 4; ++i) {
      #pragma unroll
      for (int r = 0; r < 4; ++r) {
        const int row = m0 + wr + i * 16 + lg * 4 + r;
        float v = acc[i][j][r] + bv;
        if constexpr (SK == 1 && EPI == 1) v = fmaxf(v, 0.f);
        if constexpr (sizeof(OutT) == 2) C[(size_t)row * N + col] = f2bf(v);
        else                             C[(size_t)row * N + col] = v;
      }
    }
  }
}

// ---------------------------------------------------------------- causal flash attention
// (byte-identical to round-7 passing version)
__global__ __launch_bounds__(256) void attn_kernel(
    const short* __restrict__ kqv, short* __restrict__ out)
{
  __shared__ short Kt[64][72];        // K rows (k) x d
  __shared__ short Vt[64][72];        // transposed: d x k, col k XOR-swizzled by 8*((d>>3)&7)
  __shared__ short Pl[4][16][72];     // per-wave P tile

  const int tid = threadIdx.x, w = tid >> 6, lane = tid & 63;
  const int p = blockIdx.x;           // 0..15
  const int bh = blockIdx.y;          // 0..31
  const int b = bh >> 4, h = bh & 15;
  const int q0lo = p << 6, q0hi = (31 - p) << 6;
  const int nkb = 32 - p;             // k-blocks for the hi tile
  const int lr = lane & 15, lg = lane >> 4;

  const size_t rowlo = (size_t)(b * S_ + q0lo + w * 16 + lr) * 3072 + 1024 + h * 64;
  const size_t rowhi = (size_t)(b * S_ + q0hi + w * 16 + lr) * 3072 + 1024 + h * 64;
  bf16x8 qlo[2], qhi[2];
  qlo[0] = *(const bf16x8*)&kqv[rowlo + lg * 8];
  qlo[1] = *(const bf16x8*)&kqv[rowlo + 32 + lg * 8];
  qhi[0] = *(const bf16x8*)&kqv[rowhi + lg * 8];
  qhi[1] = *(const bf16x8*)&kqv[rowhi + 32 + lg * 8];
  #pragma unroll
  for (int ks = 0; ks < 2; ++ks)
    #pragma unroll
    for (int e = 0; e < 8; ++e) {
      qlo[ks][e] = f2bf(bf2f(qlo[ks][e]) * 0.125f);
      qhi[ks][e] = f2bf(bf2f(qhi[ks][e]) * 0.125f);
    }

  f32x4 aclo[4] = {}, achi[4] = {};
  float mlo[4], llo[4], mhi[4], lhi[4];
  #pragma unroll
  for (int r = 0; r < 4; ++r) { mlo[r] = mhi[r] = -1e30f; llo[r] = lhi[r] = 0.f; }

  const int skk = tid >> 3;           // 0..31 staging row (k)
  const int sc  = (tid & 7) << 3;     // staging col (d)
  const int vws = (tid & 7) << 3;     // V write swizzle

  for (int kbi = 0; kbi < nkb; ++kbi) {
    const int kb = kbi << 6;
    #pragma unroll
    for (int i = 0; i < 2; ++i) {
      const int krow = skk + i * 32;
      const size_t gb = (size_t)(b * S_ + kb + krow) * 3072 + h * 64 + sc;
      *(bf16x8*)&Kt[krow][sc] = *(const bf16x8*)&kqv[gb];          // c=0: K
      bf16x8 vv = *(const bf16x8*)&kqv[gb + 2048];                  // c=2: V
      const int kc = krow ^ vws;
      #pragma unroll
      for (int e = 0; e < 8; ++e) Vt[sc + e][kc] = vv[e];
    }
    __syncthreads();

    auto process = [&](const bf16x8 (&qf)[2], f32x4 (&acc)[4],
                       float (&m_run)[4], float (&l_run)[4], int q0) {
      f32x4 sacc[4] = {};
      __builtin_amdgcn_s_setprio(1);
      #pragma unroll
      for (int jt = 0; jt < 4; ++jt) {
        #pragma unroll
        for (int ks = 0; ks < 2; ++ks) {
          bf16x8 kf = *(const bf16x8*)&Kt[jt * 16 + lr][ks * 32 + lg * 8];
          sacc[jt] = MFMA16(qf[ks], kf, sacc[jt]);
        }
      }
      __builtin_amdgcn_s_setprio(0);
      const bool full = (kb + 63 <= q0 + w * 16);
      float rmax[4];
      if (full) {
        #pragma unroll
        for (int r = 0; r < 4; ++r)
          rmax[r] = fmaxf(fmaxf(sacc[0][r], sacc[1][r]), fmaxf(sacc[2][r], sacc[3][r]));
      } else {
        #pragma unroll
        for (int r = 0; r < 4; ++r) rmax[r] = -1e30f;
        #pragma unroll
        for (int jt = 0; jt < 4; ++jt) {
          const int kpos = kb + jt * 16 + lr;
          #pragma unroll
          for (int r = 0; r < 4; ++r) {
            const int qrow = q0 + w * 16 + lg * 4 + r;
            float v = (kpos <= qrow) ? sacc[jt][r] : -1e30f;
            sacc[jt][r] = v;
            rmax[r] = fmaxf(rmax[r], v);
          }
        }
      }
      #pragma unroll
      for (int r = 0; r < 4; ++r) rmax[r] = dpp_max16(rmax[r]);
      int need = 0;
      #pragma unroll
      for (int r = 0; r < 4; ++r) need |= (rmax[r] > m_run[r] + 8.f) ? 1 : 0;
      if (__any(need)) {
        #pragma unroll
        for (int r = 0; r < 4; ++r) {
          const float mn = fmaxf(m_run[r], rmax[r]);
          const float al = exp2_hw((m_run[r] - mn) * LOG2E_);
          m_run[r] = mn;
          l_run[r] *= al;
          #pragma unroll
          for (int dt = 0; dt < 4; ++dt) acc[dt][r] *= al;
        }
      }
      float m2[4], rsum[4];
      #pragma unroll
      for (int r = 0; r < 4; ++r) { m2[r] = m_run[r] * LOG2E_; rsum[r] = 0.f; }
      #pragma unroll
      for (int jt = 0; jt < 4; ++jt)
        #pragma unroll
        for (int r = 0; r < 4; ++r) {
          const float pv = exp2_hw(__builtin_fmaf(sacc[jt][r], LOG2E_, -m2[r]));
          sacc[jt][r] = pv;
          rsum[r] += pv;
        }
      #pragma unroll
      for (int r = 0; r < 4; ++r) { rsum[r] = dpp_sum16(rsum[r]); l_run[r] += rsum[r]; }
      #pragma unroll
      for (int jt = 0; jt < 4; ++jt) {
        uint32_t w01, w23;
        asm("v_cvt_pk_bf16_f32 %0, %1, %2" : "=v"(w01) : "v"(sacc[jt][0]), "v"(sacc[jt][1]));
        asm("v_cvt_pk_bf16_f32 %0, %1, %2" : "=v"(w23) : "v"(sacc[jt][2]), "v"(sacc[jt][3]));
        Pl[w][lg * 4 + 0][jt * 16 + lr] = (short)(w01 & 0xffffu);
        Pl[w][lg * 4 + 1][jt * 16 + lr] = (short)(w01 >> 16);
        Pl[w][lg * 4 + 2][jt * 16 + lr] = (short)(w23 & 0xffffu);
        Pl[w][lg * 4 + 3][jt * 16 + lr] = (short)(w23 >> 16);
      }
      bf16x8 pa[2];
      pa[0] = *(const bf16x8*)&Pl[w][lr][lg * 8];
      pa[1] = *(const bf16x8*)&Pl[w][lr][32 + lg * 8];
      __builtin_amdgcn_s_setprio(1);
      #pragma unroll
      for (int dt = 0; dt < 4; ++dt) {
        const int vswz = (2 * dt + (lr >> 3)) << 3;
        #pragma unroll
        for (int ks = 0; ks < 2; ++ks) {
          bf16x8 vb = *(const bf16x8*)&Vt[dt * 16 + lr][(ks * 32 + lg * 8) ^ vswz];
          acc[dt] = MFMA16(pa[ks], vb, acc[dt]);
        }
      }
      __builtin_amdgcn_s_setprio(0);
    };

    process(qhi, achi, mhi, lhi, q0hi);
    if (kb <= q0lo + w * 16 + 15) process(qlo, aclo, mlo, llo, q0lo);
    __syncthreads();
  }

  #pragma unroll
  for (int dt = 0; dt < 4; ++dt) {
    #pragma unroll
    for (int r = 0; r < 4; ++r) {
      const int d = h * 64 + dt * 16 + lr;
      const int qlo_row = q0lo + w * 16 + lg * 4 + r;
      const int qhi_row = q0hi + w * 16 + lg * 4 + r;
      out[(size_t)(b * S_ + qlo_row) * E_ + d] = f2bf(aclo[dt][r] / llo[r]);
      out[(size_t)(b * S_ + qhi_row) * E_ + d] = f2bf(achi[dt][r] / lhi[r]);
    }
  }
}

// ---------------------------------------------------------------- residual + LayerNorm (split-K fold)
template<int FINAL>
__global__ __launch_bounds__(256) void ln_kernel(
    const float* __restrict__ y0, const float* __restrict__ y1,
    const float* __restrict__ bias, const void* __restrict__ res,
    const float* __restrict__ gam, const float* __restrict__ bet,
    void* __restrict__ outp)
{
  const int row = blockIdx.x, tid = threadIdx.x, lane = tid & 63, w = tid >> 6;
  float4 a = ((const float4*)(y0 + (size_t)row * E_))[tid];
  float4 c = ((const float4*)(y1 + (size_t)row * E_))[tid];
  float r[4] = {a.x + c.x, a.y + c.y, a.z + c.z, a.w + c.w};
  if constexpr (FINAL) {
    float4 bi = ((const float4*)bias)[tid];
    shortx4 rb = ((const shortx4*)((const short*)res + (size_t)row * E_))[tid];
    r[0] += bi.x + bf2f(rb.x); r[1] += bi.y + bf2f(rb.y);
    r[2] += bi.z + bf2f(rb.z); r[3] += bi.w + bf2f(rb.w);
  } else {
    float4 rv = ((const float4*)((const float*)res + (size_t)row * E_))[tid];
    r[0] += rv.x; r[1] += rv.y; r[2] += rv.z; r[3] += rv.w;
  }
  float s  = r[0] + r[1] + r[2] + r[3];
  float ss = r[0]*r[0] + r[1]*r[1] + r[2]*r[2] + r[3]*r[3];
  #pragma unroll
  for (int m = 32; m >= 1; m >>= 1) { s += __shfl_xor(s, m); ss += __shfl_xor(ss, m); }
  __shared__ float red[8];
  if (lane == 0) { red[w] = s; red[4 + w] = ss; }
  __syncthreads();
  s  = red[0] + red[1] + red[2] + red[3];
  ss = red[4] + red[5] + red[6] + red[7];
  const float mu  = s * (1.f / E_);
  const float var = ss * (1.f / E_) - mu * mu;
  const float rs  = rsqrtf(var + 1e-6f);
  float4 gv = ((const float4*)gam)[tid];
  float4 bv = ((const float4*)bet)[tid];
  float o0 = (r[0] - mu) * rs * gv.x + bv.x;
  float o1 = (r[1] - mu) * rs * gv.y + bv.y;
  float o2 = (r[2] - mu) * rs * gv.z + bv.z;
  float o3 = (r[3] - mu) * rs * gv.w + bv.w;
  if constexpr (FINAL) {
    float4 o; o.x = o0; o.y = o1; o.z = o2; o.w = o3;
    ((float4*)((float*)outp + (size_t)row * E_))[tid] = o;
  } else {
    shortx4 o; o.x = f2bf(o0); o.y = f2bf(o1); o.z = f2bf(o2); o.w = f2bf(o3);
    ((shortx4*)((short*)outp + (size_t)row * E_))[tid] = o;
  }
}

// ---------------------------------------------------------------- launch
// ws timeline (MB): [0-8 xb][8-14 wkqvb][14-16 wob][16-24 wupb][24-32 wdownb]
//   [32-56 kqv] -> attn [64-72 attno] -> proj [32-48 p0][48-64 p1] -> ln0 [72-80 xln]
//   -> up [32-64 hbuf] -> down [0-16 d0][80-96 d1] -> ln1.  Peak 96 MB.
extern "C" void kernel_launch(void* const* d_in, const int* in_sizes, int n_in,
                              void* d_out, int out_size, void* d_ws, size_t ws_size,
                              hipStream_t stream) {
  const float* x      = (const float*)d_in[0];
  const float* w_kqv  = (const float*)d_in[2];
  const float* w_o    = (const float*)d_in[3];
  const float* w_up   = (const float*)d_in[4];
  const float* b_up   = (const float*)d_in[5];
  const float* w_down = (const float*)d_in[6];
  const float* b_down = (const float*)d_in[7];
  const float* g1     = (const float*)d_in[8];
  const float* b1     = (const float*)d_in[9];
  const float* g2     = (const float*)d_in[10];
  const float* b2     = (const float*)d_in[11];
  float* out = (float*)d_out;

  char* ws = (char*)d_ws;
  short* xb     = (short*)(ws);
  short* wkqvb  = (short*)(ws + ((size_t)8  << 20));
  short* wob    = (short*)(ws + ((size_t)14 << 20));
  short* wupb   = (short*)(ws + ((size_t)16 << 20));
  short* wdownb = (short*)(ws + ((size_t)24 << 20));
  short* kqv    = (short*)(ws + ((size_t)32 << 20));
  float* proj0  = (float*)(ws + ((size_t)32 << 20));
  float* proj1  = (float*)(ws + ((size_t)48 << 20));
  short* hbuf   = (short*)(ws + ((size_t)32 << 20));
  short* attno  = (short*)(ws + ((size_t)64 << 20));
  short* xln    = (short*)(ws + ((size_t)72 << 20));
  float* down0  = (float*)(ws);
  float* down1  = (float*)(ws + ((size_t)80 << 20));

  cast_all<<<2048, 256, 0, stream>>>(x, w_kqv, w_o, w_up, w_down,
                                     xb, wkqvb, wob, wupb, wdownb);

  gemm_bt<1, 0, short><<<24 * 32, 256, 0, stream>>>(xb, wkqvb, kqv, nullptr, nullptr, M_, 3 * E_, E_);
  attn_kernel<<<dim3(16, B_ * H_), 256, 0, stream>>>(kqv, attno);
  gemm_bt<2, 0, float><<<dim3(256, 2), 256, 0, stream>>>(attno, wob, proj0, proj1, nullptr, M_, E_, E_);
  ln_kernel<0><<<M_, 256, 0, stream>>>(proj0, proj1, nullptr, x, g1, b1, xln);
  gemm_bt<1, 1, short><<<32 * 32, 256, 0, stream>>>(xln, wupb, hbuf, nullptr, b_up, M_, FF_, E_);
  gemm_bt<2, 0, float><<<dim3(256, 2), 256, 0, stream>>>(hbuf, wdownb, down0, down1, nullptr, M_, E_, FF_);
  ln_kernel<1><<<M_, 256, 0, stream>>>(down0, down1, b_down, xln, g2, b2, out);
}